// Round 15
// baseline (262.043 us; speedup 1.0000x reference)
//
#include <hip/hip_runtime.h>

typedef __bf16 bf16x8 __attribute__((ext_vector_type(8)));
typedef __bf16 bf16x4 __attribute__((ext_vector_type(4)));
typedef float f32x4 __attribute__((ext_vector_type(4)));

#define B_TOT   16384
#define DM      512
#define NF      64
#define KU      64   // K for final GEMM: 8 G + 36 sym pairs + 1 eye + 19 zero

#define MFMA16(a,b,c) __builtin_amdgcn_mfma_f32_16x16x32_bf16(a,b,c,0,0,0)

static __device__ __forceinline__ void gload_lds16(const void* g, void* l) {
  __builtin_amdgcn_global_load_lds((const __attribute__((address_space(1))) char*)g,
                                   (__attribute__((address_space(3))) char*)l, 16, 0, 0);
}

static __device__ __forceinline__ float fast_exp2(float x) {
  return __builtin_amdgcn_exp2f(x);
}
static __device__ __forceinline__ float fast_rcp(float x) {
  return __builtin_amdgcn_rcpf(x);
}

static __device__ __forceinline__ bf16x8 cvt8(f32x4 lo, f32x4 hi) {
  bf16x8 r;
  r[0]=(__bf16)lo[0]; r[1]=(__bf16)lo[1]; r[2]=(__bf16)lo[2]; r[3]=(__bf16)lo[3];
  r[4]=(__bf16)hi[0]; r[5]=(__bf16)hi[1]; r[6]=(__bf16)hi[2]; r[7]=(__bf16)hi[3];
  return r;
}

// ---------------- prep: W1->bf16, w2p pack, Vt build ----------------
// grid 298: [0,256) W1 cvt; [256,258) w2p; [258,294) pair-product cols; [294,298) static cols
__global__ __launch_bounds__(256) void prep_kernel(const float* __restrict__ W1,
                                                   const float* __restrict__ W2,
                                                   const float* __restrict__ gen,
                                                   __bf16* __restrict__ W1b,
                                                   __bf16* __restrict__ w2p,
                                                   __bf16* __restrict__ Vt) {
  const int bid = blockIdx.x, tid = threadIdx.x;
  __shared__ float Ga[NF*NF];
  __shared__ float Gb[NF*NF];
  if (bid < 256) {
    const int i = (bid*256 + tid)*4;
    float4 v = *(const float4*)(W1 + i);
    bf16x4 o; o[0]=(__bf16)v.x; o[1]=(__bf16)v.y; o[2]=(__bf16)v.z; o[3]=(__bf16)v.w;
    *(bf16x4*)(W1b + i) = o;
  } else if (bid < 258) {
    const int n = (bid-256)*256 + tid;
    bf16x8 o;
    #pragma unroll
    for (int r = 0; r < 8; ++r) o[r] = (__bf16)W2[r*DM + n];
    *(bf16x8*)(w2p + n*8) = o;
  } else if (bid < 294) {
    // pair p -> (r,s), r<=s: col 8+p = G_r G_s + (r!=s) G_s G_r
    const int p = bid - 258;
    int r = (p>=8)+(p>=15)+(p>=21)+(p>=26)+(p>=30)+(p>=33)+(p>=35);
    const int baser = r*8 - ((r*(r-1))>>1);
    const int s = r + p - baser;
    for (int i = tid; i < NF*NF; i += 256) {
      Ga[i] = gen[r*NF*NF + i];
      Gb[i] = gen[s*NF*NF + i];
    }
    __syncthreads();
    const int i  = tid >> 2;
    const int j0 = (tid & 3) * 16;
    float acc[16];
    #pragma unroll
    for (int jj = 0; jj < 16; ++jj) acc[jj] = 0.f;
    for (int k = 0; k < NF; ++k) {
      float a = Ga[i*NF + k];
      #pragma unroll
      for (int jj = 0; jj < 16; ++jj) acc[jj] += a * Gb[k*NF + j0 + jj];
    }
    if (r != s) {
      for (int k = 0; k < NF; ++k) {
        float a = Gb[i*NF + k];
        #pragma unroll
        for (int jj = 0; jj < 16; ++jj) acc[jj] += a * Ga[k*NF + j0 + jj];
      }
    }
    #pragma unroll
    for (int jj = 0; jj < 16; ++jj)
      Vt[(size_t)(i*NF + j0 + jj)*KU + 8 + p] = (__bf16)acc[jj];
  } else {
    // static cols: 0..7 = G_r[ij]; 44 = eye; 45..63 = 0
    const int q = bid - 294;
    #pragma unroll
    for (int v = 0; v < 4; ++v) {
      const int ij = q*1024 + tid*4 + v;
      bf16x8 g8;
      #pragma unroll
      for (int r = 0; r < 8; ++r) g8[r] = (__bf16)gen[r*NF*NF + ij];
      __bf16* row = Vt + (size_t)ij*KU;
      *(bf16x8*)row = g8;
      const float eye = ((ij >> 6) == (ij & 63)) ? 1.f : 0.f;
      bf16x4 e4; e4[0] = (__bf16)eye; e4[1] = (__bf16)0.f; e4[2] = (__bf16)0.f; e4[3] = (__bf16)0.f;
      *(bf16x4*)(row + 44) = e4;
      bf16x8 z8;
      #pragma unroll
      for (int k = 0; k < 8; ++k) z8[k] = (__bf16)0.f;
      *(bf16x8*)(row + 48) = z8;
      *(bf16x8*)(row + 56) = z8;
    }
  }
}

// ---------------- K1a (MEASUREMENT build): 6 redundant passes ----------------
// tile = bid % 512 -> the 512-WG mlp1 grid is executed 6x with identical writes
// (benign; same values). Purpose: dispatch dur ~6x mlp1 surfaces in the top-5
// table WITH counters (MfmaUtil/VALUBusy/Occupancy/FETCH) — first direct mlp1
// observation. Inner structure = R10/R14's verified mlp1, byte-identical math.
__global__ __launch_bounds__(256, 2) void mlp1_kernel(
    const float* __restrict__ xs, const float* __restrict__ xe,
    const __bf16* __restrict__ W1b, const float* __restrict__ b1,
    __bf16* __restrict__ Gsb, __bf16* __restrict__ Geb) {
  const int bid = blockIdx.x % 512;   // 6 duplicate passes
  const int mat = bid & 1;
  const int mtile = bid >> 1;
  const int m0 = mtile*64;
  const float* __restrict__ X = mat ? xe : xs;
  __bf16* __restrict__ G = mat ? Geb : Gsb;

  __shared__ __bf16 As[2][64*64];   // 2 x 8 KB; chunk c of row at slot c^(row&7)
  __shared__ __bf16 Bs[512*64];     // 64 KB;   chunk c of row at slot c^((row>>3)&7)

  const int tid = threadIdx.x;
  const int l = tid & 63, w = tid >> 6;
  const int lc = l & 15, lg = l >> 4;

  const int arow = tid >> 2;      // 0..63
  const int aq   = tid & 3;
  const float* asrc = X + (size_t)(m0 + arow)*DM + aq*16;

  auto stageB = [&](int k0) {
    #pragma unroll
    for (int c = 0; c < 16; ++c) {
      const int row = c*32 + (tid >> 3);
      const int sp = (tid & 7) ^ ((row >> 3) & 7);
      gload_lds16(W1b + (size_t)row*DM + k0 + sp*8,
                  (char*)Bs + c*4096 + tid*16);
    }
  };

  f32x4 ar[4];
  auto loadA = [&](int k0) {
    const float* p = asrc + k0;
    ar[0] = *(const f32x4*)(p);
    ar[1] = *(const f32x4*)(p + 4);
    ar[2] = *(const f32x4*)(p + 8);
    ar[3] = *(const f32x4*)(p + 12);
  };
  auto writeA = [&](int buf) {
    const int e = arow & 7;
    *(bf16x8*)(&As[buf][0] + arow*64 + (((aq*2    ) ^ e)*8)) = cvt8(ar[0], ar[1]);
    *(bf16x8*)(&As[buf][0] + arow*64 + (((aq*2 + 1) ^ e)*8)) = cvt8(ar[2], ar[3]);
  };

  f32x4 acc[4][8];
  #pragma unroll
  for (int a = 0; a < 4; ++a)
    #pragma unroll
    for (int b = 0; b < 8; ++b) acc[a][b] = (f32x4)0.f;

  loadA(0);
  stageB(0);
  writeA(0);

  for (int ks = 0; ks < 8; ++ks) {
    const int cb = ks & 1, nb = cb ^ 1;
    __syncthreads();                 // sync1: staging(ks) visible (vmcnt+lgkm)
    if (ks < 7) loadA((ks+1)*64);    // HBM loads issue early, drain after compute
    #pragma unroll
    for (int kk = 0; kk < 2; ++kk) {
      bf16x8 aF[4], bF[8];
      #pragma unroll
      for (int mt = 0; mt < 4; ++mt) {
        const int row = mt*16 + lc;
        const int sp = (kk*4 + lg) ^ (row & 7);
        aF[mt] = *(const bf16x8*)(&As[cb][0] + row*64 + sp*8);
      }
      #pragma unroll
      for (int nt = 0; nt < 8; ++nt) {
        const int row = w*128 + lc*8 + nt;
        const int sp = (kk*4 + lg) ^ ((row >> 3) & 7);
        bF[nt] = *(const bf16x8*)(Bs + row*64 + sp*8);
      }
      #pragma unroll
      for (int mt = 0; mt < 4; ++mt)
        #pragma unroll
        for (int nt = 0; nt < 8; ++nt)
          acc[mt][nt] = MFMA16(aF[mt], bF[nt], acc[mt][nt]);
    }
    if (ks < 7) {
      __syncthreads();               // sync2: all Bs/As reads for ks done
      stageB((ks+1)*64);
      writeA(nb);
    }
  }

  // epilogue: +b1, cvt bf16, per-lane bf16x8 stores (n = w*128 + lc*8 .. +8)
  f32x4 b1lo = *(const f32x4*)(b1 + w*128 + lc*8);
  f32x4 b1hi = *(const f32x4*)(b1 + w*128 + lc*8 + 4);
  #pragma unroll
  for (int mt = 0; mt < 4; ++mt) {
    #pragma unroll
    for (int rg = 0; rg < 4; ++rg) {
      const int m = m0 + mt*16 + lg*4 + rg;
      bf16x8 o;
      #pragma unroll
      for (int nt = 0; nt < 8; ++nt) {
        const float bb = (nt < 4) ? b1lo[nt] : b1hi[nt-4];
        o[nt] = (__bf16)(acc[mt][nt][rg] + bb);
      }
      *(bf16x8*)(G + (size_t)m*DM + w*128 + lc*8) = o;
    }
  }
}

// ---------------- K1b: coefficients ---------------- (unchanged)
__global__ __launch_bounds__(256, 4) void coeff2_kernel(
    const __bf16* __restrict__ Gsb, const __bf16* __restrict__ Geb,
    const __bf16* __restrict__ w2p, const float* __restrict__ b2,
    const float* __restrict__ scale_p, __bf16* __restrict__ u) {
  const int tid = threadIdx.x;
  const int wv = tid >> 6, l = tid & 63;
  const int ls = l & 15;
  const int rib = wv*4 + (l >> 4);       // row in block, 0..15
  const int row = blockIdx.x*16 + rib;
  const size_t rb = (size_t)row * DM;

  __shared__ float cshr[16][8];

  float pz[4][8];
  #pragma unroll
  for (int st = 0; st < 4; ++st)
    #pragma unroll
    for (int r = 0; r < 8; ++r) pz[st][r] = 0.f;

  #pragma unroll
  for (int c = 0; c < 4; ++c) {
    const int nb = c*128 + ls*8;
    bf16x8 s8 = *(const bf16x8*)(Gsb + rb + nb);
    bf16x8 e8 = *(const bf16x8*)(Geb + rb + nb);
    #pragma unroll
    for (int i = 0; i < 8; ++i) {
      const float sv = (float)s8[i];
      const float dv = (float)e8[i] - sv;
      bf16x8 wv8 = *(const bf16x8*)(w2p + (size_t)(nb + i)*8);
      float w2f[8];
      #pragma unroll
      for (int r = 0; r < 8; ++r) w2f[r] = (float)wv8[r];
      #pragma unroll
      for (int st = 0; st < 4; ++st) {
        const float t = 0.125f + 0.25f*(float)st;
        const float mid = fmaf(t, dv, sv);
        const float g = mid * fast_rcp(1.f + fast_exp2(-2.4554669f * mid));
        #pragma unroll
        for (int r = 0; r < 8; ++r) pz[st][r] = fmaf(g, w2f[r], pz[st][r]);
      }
    }
  }

  #pragma unroll
  for (int st = 0; st < 4; ++st)
    #pragma unroll
    for (int r = 0; r < 8; ++r) {
      float v = pz[st][r];
      v += __shfl_xor(v, 1); v += __shfl_xor(v, 2);
      v += __shfl_xor(v, 4); v += __shfl_xor(v, 8);
      pz[st][r] = v;
    }

  const int rown = ls & 7;
  const float b2r = b2[rown];
  float sum = 0.f;
  #pragma unroll
  for (int st = 0; st < 4; ++st) {
    const float z = pz[st][rown] + b2r;
    const float te = fast_exp2(2.8853901f * z);   // e^(2z); inf-safe: tanh->1
    sum += 1.f - 2.f * fast_rcp(te + 1.f);
  }
  const float cs_own = sum * 0.25f * (*scale_p);  // * dt * scale
  if (ls < 8) cshr[rib][ls] = cs_own;
  __syncthreads();

  bf16x4 o;
  #pragma unroll
  for (int j = 0; j < 4; ++j) {
    const int k = ls*4 + j;
    float val;
    if (k < 8) {
      val = cshr[rib][k];
    } else if (k < 44) {
      const int p = k - 8;
      int r = (p>=8)+(p>=15)+(p>=21)+(p>=26)+(p>=30)+(p>=33)+(p>=35);
      const int baser = r*8 - ((r*(r-1))>>1);
      const int s2 = r + p - baser;
      val = 0.5f * cshr[rib][r] * cshr[rib][s2];
    } else if (k == 44) {
      val = 1.f;
    } else {
      val = 0.f;
    }
    o[j] = (__bf16)val;
  }
  *(bf16x4*)(u + (size_t)row*KU + ls*4) = o;
}

// ---------------- K3: out[b][ij] = sum_k u[b][k] * Vt[ij][k]  (K=64) ----------------
// (R14's version: LDS store-coalescing epilogue; neutral vs R10 but keep.)
__global__ __launch_bounds__(256) void out_gemm_kernel(
    const __bf16* __restrict__ u, const __bf16* __restrict__ Vt,
    float* __restrict__ out) {
  __shared__ float Ls[16*256];   // 16 KB store-coalescing buffer
  const int bid = blockIdx.x;
  const int mb = bid >> 4, nbq = bid & 15;
  const int tid = threadIdx.x;
  const int l = tid & 63, wv = tid >> 6;
  const int lc = l & 15, lg = l >> 4;
  const int m0 = mb*64;
  const int n0 = nbq*256 + wv*64;

  f32x4 acc[4][4];
  #pragma unroll
  for (int a = 0; a < 4; ++a)
    #pragma unroll
    for (int b = 0; b < 4; ++b) acc[a][b] = (f32x4)0.f;

  #pragma unroll
  for (int ks = 0; ks < 2; ++ks) {
    const int k0 = ks*32 + lg*8;
    bf16x8 aF[4], bF[4];
    #pragma unroll
    for (int a = 0; a < 4; ++a)
      aF[a] = *(const bf16x8*)(u + (size_t)(m0 + a*16 + lc)*KU + k0);
    #pragma unroll
    for (int b = 0; b < 4; ++b)
      bF[b] = *(const bf16x8*)(Vt + (size_t)(n0 + lc*4 + b)*KU + k0);
    #pragma unroll
    for (int a = 0; a < 4; ++a)
      #pragma unroll
      for (int b = 0; b < 4; ++b)
        acc[a][b] = MFMA16(aF[a], bF[b], acc[a][b]);
  }

  #pragma unroll
  for (int a = 0; a < 4; ++a) {
    #pragma unroll
    for (int rg = 0; rg < 4; ++rg) {
      f32x4 o; o[0] = acc[a][0][rg]; o[1] = acc[a][1][rg];
      o[2] = acc[a][2][rg]; o[3] = acc[a][3][rg];
      *(f32x4*)(Ls + (lg*4 + rg)*256 + wv*64 + lc*4) = o;
    }
    __syncthreads();
    #pragma unroll
    for (int rr = 0; rr < 4; ++rr) {
      const int row = rr*4 + wv;
      f32x4 o = *(const f32x4*)(Ls + row*256 + l*4);
      *(f32x4*)(out + (size_t)(m0 + a*16 + row)*4096 + nbq*256 + l*4) = o;
    }
    if (a < 3) __syncthreads();
  }
}

extern "C" void kernel_launch(void* const* d_in, const int* in_sizes, int n_in,
                              void* d_out, int out_size, void* d_ws, size_t ws_size,
                              hipStream_t stream) {
  const float* xs    = (const float*)d_in[0];
  const float* xe    = (const float*)d_in[1];
  const float* W1    = (const float*)d_in[2];
  const float* b1    = (const float*)d_in[3];
  const float* W2    = (const float*)d_in[4];
  const float* b2    = (const float*)d_in[5];
  const float* gen   = (const float*)d_in[6];
  const float* scale = (const float*)d_in[7];

  char* ws = (char*)d_ws;
  __bf16* W1b = (__bf16*)ws;                                    // 512 KB
  __bf16* u   = (__bf16*)(ws + 512*1024);                       // 2 MB
  __bf16* Vt  = (__bf16*)(ws + 512*1024 + 2*1024*1024);         // 512 KB
  __bf16* w2p = (__bf16*)(ws + 512*1024 + 2*1024*1024 + 512*1024); // 8 KB

  // Gs/Ge scratch lives in d_out (32 MB of 268), fully overwritten by K3.
  char* outc = (char*)d_out;
  __bf16* Gsb = (__bf16*)outc;
  __bf16* Geb = (__bf16*)(outc + (size_t)16*1024*1024);

  prep_kernel<<<298, 256, 0, stream>>>(W1, W2, gen, W1b, w2p, Vt);
  // MEASUREMENT dispatch: 6 redundant mlp1 passes (3072 WGs) so this kernel's
  // duration (~6x mlp1) exceeds the fill kernels and surfaces in top-5 w/ counters.
  mlp1_kernel<<<6*512, 256, 0, stream>>>(xs, xe, W1b, b1, Gsb, Geb);
  coeff2_kernel<<<B_TOT/16, 256, 0, stream>>>(Gsb, Geb, w2p, b2, scale, u);
  out_gemm_kernel<<<256*16, 256, 0, stream>>>(u, Vt, (float*)d_out);
}

// Round 16
// 258.359 us; speedup vs baseline: 1.0143x; 1.0143x over previous
//
#include <hip/hip_runtime.h>

typedef __bf16 bf16x8 __attribute__((ext_vector_type(8)));
typedef __bf16 bf16x4 __attribute__((ext_vector_type(4)));
typedef float f32x4 __attribute__((ext_vector_type(4)));

#define B_TOT   16384
#define DM      512
#define NF      64
#define KU      64   // K for final GEMM: 8 G + 36 sym pairs + 1 eye + 19 zero

#define MFMA16(a,b,c) __builtin_amdgcn_mfma_f32_16x16x32_bf16(a,b,c,0,0,0)

static __device__ __forceinline__ void gload_lds16(const void* g, void* l) {
  __builtin_amdgcn_global_load_lds((const __attribute__((address_space(1))) char*)g,
                                   (__attribute__((address_space(3))) char*)l, 16, 0, 0);
}

static __device__ __forceinline__ float fast_exp2(float x) {
  return __builtin_amdgcn_exp2f(x);
}
static __device__ __forceinline__ float fast_rcp(float x) {
  return __builtin_amdgcn_rcpf(x);
}

static __device__ __forceinline__ bf16x8 cvt8(f32x4 lo, f32x4 hi) {
  bf16x8 r;
  r[0]=(__bf16)lo[0]; r[1]=(__bf16)lo[1]; r[2]=(__bf16)lo[2]; r[3]=(__bf16)lo[3];
  r[4]=(__bf16)hi[0]; r[5]=(__bf16)hi[1]; r[6]=(__bf16)hi[2]; r[7]=(__bf16)hi[3];
  return r;
}

// ---------------- prep: W1->bf16, w2p pack, Vt build ---------------- (unchanged)
__global__ __launch_bounds__(256) void prep_kernel(const float* __restrict__ W1,
                                                   const float* __restrict__ W2,
                                                   const float* __restrict__ gen,
                                                   __bf16* __restrict__ W1b,
                                                   __bf16* __restrict__ w2p,
                                                   __bf16* __restrict__ Vt) {
  const int bid = blockIdx.x, tid = threadIdx.x;
  __shared__ float Ga[NF*NF];
  __shared__ float Gb[NF*NF];
  if (bid < 256) {
    const int i = (bid*256 + tid)*4;
    float4 v = *(const float4*)(W1 + i);
    bf16x4 o; o[0]=(__bf16)v.x; o[1]=(__bf16)v.y; o[2]=(__bf16)v.z; o[3]=(__bf16)v.w;
    *(bf16x4*)(W1b + i) = o;
  } else if (bid < 258) {
    const int n = (bid-256)*256 + tid;
    bf16x8 o;
    #pragma unroll
    for (int r = 0; r < 8; ++r) o[r] = (__bf16)W2[r*DM + n];
    *(bf16x8*)(w2p + n*8) = o;
  } else if (bid < 294) {
    const int p = bid - 258;
    int r = (p>=8)+(p>=15)+(p>=21)+(p>=26)+(p>=30)+(p>=33)+(p>=35);
    const int baser = r*8 - ((r*(r-1))>>1);
    const int s = r + p - baser;
    for (int i = tid; i < NF*NF; i += 256) {
      Ga[i] = gen[r*NF*NF + i];
      Gb[i] = gen[s*NF*NF + i];
    }
    __syncthreads();
    const int i  = tid >> 2;
    const int j0 = (tid & 3) * 16;
    float acc[16];
    #pragma unroll
    for (int jj = 0; jj < 16; ++jj) acc[jj] = 0.f;
    for (int k = 0; k < NF; ++k) {
      float a = Ga[i*NF + k];
      #pragma unroll
      for (int jj = 0; jj < 16; ++jj) acc[jj] += a * Gb[k*NF + j0 + jj];
    }
    if (r != s) {
      for (int k = 0; k < NF; ++k) {
        float a = Gb[i*NF + k];
        #pragma unroll
        for (int jj = 0; jj < 16; ++jj) acc[jj] += a * Ga[k*NF + j0 + jj];
      }
    }
    #pragma unroll
    for (int jj = 0; jj < 16; ++jj)
      Vt[(size_t)(i*NF + j0 + jj)*KU + 8 + p] = (__bf16)acc[jj];
  } else {
    const int q = bid - 294;
    #pragma unroll
    for (int v = 0; v < 4; ++v) {
      const int ij = q*1024 + tid*4 + v;
      bf16x8 g8;
      #pragma unroll
      for (int r = 0; r < 8; ++r) g8[r] = (__bf16)gen[r*NF*NF + ij];
      __bf16* row = Vt + (size_t)ij*KU;
      *(bf16x8*)row = g8;
      const float eye = ((ij >> 6) == (ij & 63)) ? 1.f : 0.f;
      bf16x4 e4; e4[0] = (__bf16)eye; e4[1] = (__bf16)0.f; e4[2] = (__bf16)0.f; e4[3] = (__bf16)0.f;
      *(bf16x4*)(row + 44) = e4;
      bf16x8 z8;
      #pragma unroll
      for (int k = 0; k < 8; ++k) z8[k] = (__bf16)0.f;
      *(bf16x8*)(row + 48) = z8;
      *(bf16x8*)(row + 56) = z8;
    }
  }
}

// ---------------- fused: mlp (R10 structure) + coeff (coeff2 replica) + outGEMM (R10-K3) ----
// grid 256 x 512 thr (8 waves), 1 WG/CU, 96 KB LDS pool:
//   mlp:  Bs = pool[0,64K)  As = pool[64K,96K) = [mat][dbuf][64x64 bf16]
//   epi:  Gh = pool[0,64K)  = [mat][32 rows x 512 bf16] (per row-half)
//         u_lds = pool[64K,72K), cshr = pool[72K,74K)
// Every region reuse is preceded by __syncthreads (R6's race was the missing one).
// All math replicates the R14 pipeline bit-exactly (G through bf16, coeff2's
// slice/shfl order, K3's MFMA order) -> output must be BIT-IDENTICAL.
__global__ __launch_bounds__(512, 2) void fused_kernel(
    const float* __restrict__ xs, const float* __restrict__ xe,
    const __bf16* __restrict__ W1b, const float* __restrict__ b1,
    const __bf16* __restrict__ w2p, const float* __restrict__ b2,
    const float* __restrict__ scale_p, const __bf16* __restrict__ Vt,
    float* __restrict__ out) {
  __shared__ __align__(16) char pool[98304];

  const int tid = threadIdx.x;
  const int l = tid & 63, w = tid >> 6;      // 8 waves
  const int lc = l & 15, lg = l >> 4;
  const int m0 = blockIdx.x * 64;
  const int mat = w >> 2;                    // waves 0-3: xs, 4-7: xe
  const int strip = (w & 3) * 128;

  // ---- A staging (R10 map, doubled for 2 mats)
  const int amat = tid >> 8, tt = tid & 255;
  const int arow = tt >> 2, aq = tt & 3;
  const float* asrc = (amat ? xe : xs) + (size_t)(m0 + arow)*DM + aq*16;
  f32x4 ar[4];
  auto loadA = [&](int k0) {
    const float* p = asrc + k0;
    ar[0] = *(const f32x4*)(p);
    ar[1] = *(const f32x4*)(p + 4);
    ar[2] = *(const f32x4*)(p + 8);
    ar[3] = *(const f32x4*)(p + 12);
  };
  auto writeA = [&](int buf) {
    char* base = pool + 65536 + amat*16384 + buf*8192;
    const int e = arow & 7;
    *(bf16x8*)(base + arow*128 + (((aq*2    ) ^ e)*16)) = cvt8(ar[0], ar[1]);
    *(bf16x8*)(base + arow*128 + (((aq*2 + 1) ^ e)*16)) = cvt8(ar[2], ar[3]);
  };
  auto stageB = [&](int k0) {
    #pragma unroll
    for (int c = 0; c < 8; ++c) {
      const int row = c*64 + (tid >> 3);
      const int sp = (tid & 7) ^ ((row >> 3) & 7);
      gload_lds16(W1b + (size_t)row*DM + k0 + sp*8, pool + c*8192 + tid*16);
    }
  };

  f32x4 acc[4][8];
  #pragma unroll
  for (int a = 0; a < 4; ++a)
    #pragma unroll
    for (int b = 0; b < 8; ++b) acc[a][b] = (f32x4)0.f;

  loadA(0);
  stageB(0);
  writeA(0);

  for (int ks = 0; ks < 8; ++ks) {
    const int cb = ks & 1, nbuf = cb ^ 1;
    __syncthreads();                 // staging(ks) visible
    if (ks < 7) loadA((ks+1)*64);    // HBM loads early, drain after compute
    #pragma unroll
    for (int kk = 0; kk < 2; ++kk) {
      bf16x8 aF[4], bF[8];
      #pragma unroll
      for (int mt = 0; mt < 4; ++mt) {
        const int row = mt*16 + lc;
        const int sp = (kk*4 + lg) ^ (row & 7);
        aF[mt] = *(const bf16x8*)(pool + 65536 + mat*16384 + cb*8192 + row*128 + sp*16);
      }
      #pragma unroll
      for (int nt = 0; nt < 8; ++nt) {
        const int row = strip + lc*8 + nt;
        const int sp = (kk*4 + lg) ^ ((row >> 3) & 7);
        bF[nt] = *(const bf16x8*)(pool + row*128 + sp*16);
      }
      #pragma unroll
      for (int mt = 0; mt < 4; ++mt)
        #pragma unroll
        for (int nt = 0; nt < 8; ++nt)
          acc[mt][nt] = MFMA16(aF[mt], bF[nt], acc[mt][nt]);
    }
    if (ks < 7) {
      __syncthreads();               // all reads of ks done
      stageB((ks+1)*64);
      writeA(nbuf);
    }
  }

  // ---- epilogue: coefficients (2 row-halves of 32), coeff2-replica math
  f32x4 b1lo = *(const f32x4*)(b1 + strip + lc*8);
  f32x4 b1hi = *(const f32x4*)(b1 + strip + lc*8 + 4);
  const float sclv = *scale_p;
  float* cshr = (float*)(pool + 65536 + 8192);   // [64][8]

  for (int h = 0; h < 2; ++h) {
    __syncthreads();   // h=0: Bs reads done; h=1: Gh reads of h=0 done
    // write G half into pool[0,64K): [mat][lr][512 bf16], slot-swizzled ^(lr&7)
    #pragma unroll
    for (int mt2 = 0; mt2 < 2; ++mt2) {
      const int mt = h*2 + mt2;
      #pragma unroll
      for (int rg = 0; rg < 4; ++rg) {
        const int lr = mt2*16 + lg*4 + rg;
        bf16x8 o;
        #pragma unroll
        for (int nt = 0; nt < 8; ++nt) {
          const float bb = (nt < 4) ? b1lo[nt] : b1hi[nt-4];
          o[nt] = (__bf16)(acc[mt][nt][rg] + bb);
        }
        *(bf16x8*)(pool + mat*32768 + lr*1024 + (((((w&3)*16 + lc)) ^ (lr & 7))*16)) = o;
      }
    }
    __syncthreads();
    // coeff2 replica: wave w handles rows lr = w*4 + (l>>4); 16 slices
    {
      const int lr = w*4 + (l >> 4);
      const int ls = l & 15;
      float pz[4][8];
      #pragma unroll
      for (int st = 0; st < 4; ++st)
        #pragma unroll
        for (int r = 0; r < 8; ++r) pz[st][r] = 0.f;

      #pragma unroll
      for (int c = 0; c < 4; ++c) {
        const int nb = c*128 + ls*8;
        const int sb = (((c*16 + ls) ^ (lr & 7))*16);
        bf16x8 s8 = *(const bf16x8*)(pool +         lr*1024 + sb);
        bf16x8 e8 = *(const bf16x8*)(pool + 32768 + lr*1024 + sb);
        #pragma unroll
        for (int i = 0; i < 8; ++i) {
          const float sv = (float)s8[i];
          const float dv = (float)e8[i] - sv;
          bf16x8 wv8 = *(const bf16x8*)(w2p + (size_t)(nb + i)*8);
          float w2f[8];
          #pragma unroll
          for (int r = 0; r < 8; ++r) w2f[r] = (float)wv8[r];
          #pragma unroll
          for (int st = 0; st < 4; ++st) {
            const float t = 0.125f + 0.25f*(float)st;
            const float mid = fmaf(t, dv, sv);
            const float g = mid * fast_rcp(1.f + fast_exp2(-2.4554669f * mid));
            #pragma unroll
            for (int r = 0; r < 8; ++r) pz[st][r] = fmaf(g, w2f[r], pz[st][r]);
          }
        }
      }
      #pragma unroll
      for (int st = 0; st < 4; ++st)
        #pragma unroll
        for (int r = 0; r < 8; ++r) {
          float v = pz[st][r];
          v += __shfl_xor(v, 1); v += __shfl_xor(v, 2);
          v += __shfl_xor(v, 4); v += __shfl_xor(v, 8);
          pz[st][r] = v;
        }
      const int rown = ls & 7;
      const float b2r = b2[rown];
      float sum = 0.f;
      #pragma unroll
      for (int st = 0; st < 4; ++st) {
        const float z = pz[st][rown] + b2r;
        const float te = fast_exp2(2.8853901f * z);
        sum += 1.f - 2.f * fast_rcp(te + 1.f);
      }
      const float cs_own = sum * 0.25f * sclv;
      if (ls < 8) cshr[(h*32 + lr)*8 + ls] = cs_own;
    }
  }
  __syncthreads();

  // ---- u build into u_lds (pool[64K,72K)), slot-swizzled ^(row&7)
  {
    const int row = tid >> 3;
    const float* csr = cshr + row*8;
    #pragma unroll
    for (int j = 0; j < 2; ++j) {
      const int lsq = (tid & 7)*2 + j;
      bf16x4 o;
      #pragma unroll
      for (int jj = 0; jj < 4; ++jj) {
        const int k = lsq*4 + jj;
        float val;
        if (k < 8) {
          val = csr[k];
        } else if (k < 44) {
          const int p = k - 8;
          int r = (p>=8)+(p>=15)+(p>=21)+(p>=26)+(p>=30)+(p>=33)+(p>=35);
          const int baser = r*8 - ((r*(r-1))>>1);
          const int s2 = r + p - baser;
          val = 0.5f * csr[r] * csr[s2];
        } else if (k == 44) {
          val = 1.f;
        } else {
          val = 0.f;
        }
        o[jj] = (__bf16)val;
      }
      *(bf16x4*)(pool + 65536 + row*128 + (((lsq >> 1) ^ (row & 7))*16) + (lsq & 1)*8) = o;
    }
  }
  __syncthreads();

  // ---- K3 phase (R10-K3 replica): wave w covers cols [w*512, w*512+512), 8 units
  bf16x8 uF[4][2];
  #pragma unroll
  for (int a = 0; a < 4; ++a)
    #pragma unroll
    for (int ks = 0; ks < 2; ++ks) {
      const int row = a*16 + lc;
      uF[a][ks] = *(const bf16x8*)(pool + 65536 + row*128 + (((ks*4 + lg) ^ (row & 7))*16));
    }
  for (int u8 = 0; u8 < 8; ++u8) {
    const int n0 = w*512 + u8*64;
    f32x4 acc3[4][4];
    #pragma unroll
    for (int a = 0; a < 4; ++a)
      #pragma unroll
      for (int b = 0; b < 4; ++b) acc3[a][b] = (f32x4)0.f;
    #pragma unroll
    for (int ks = 0; ks < 2; ++ks) {
      bf16x8 bF[4];
      #pragma unroll
      for (int b = 0; b < 4; ++b)
        bF[b] = *(const bf16x8*)(Vt + (size_t)(n0 + lc*4 + b)*KU + ks*32 + lg*8);
      #pragma unroll
      for (int a = 0; a < 4; ++a)
        #pragma unroll
        for (int b = 0; b < 4; ++b)
          acc3[a][b] = MFMA16(uF[a][ks], bF[b], acc3[a][b]);
    }
    #pragma unroll
    for (int a = 0; a < 4; ++a)
      #pragma unroll
      for (int rg = 0; rg < 4; ++rg) {
        f32x4 o; o[0] = acc3[a][0][rg]; o[1] = acc3[a][1][rg];
        o[2] = acc3[a][2][rg]; o[3] = acc3[a][3][rg];
        *(f32x4*)(out + (size_t)(m0 + a*16 + lg*4 + rg)*4096 + n0 + lc*4) = o;
      }
  }
}

extern "C" void kernel_launch(void* const* d_in, const int* in_sizes, int n_in,
                              void* d_out, int out_size, void* d_ws, size_t ws_size,
                              hipStream_t stream) {
  const float* xs    = (const float*)d_in[0];
  const float* xe    = (const float*)d_in[1];
  const float* W1    = (const float*)d_in[2];
  const float* b1    = (const float*)d_in[3];
  const float* W2    = (const float*)d_in[4];
  const float* b2    = (const float*)d_in[5];
  const float* gen   = (const float*)d_in[6];
  const float* scale = (const float*)d_in[7];

  char* ws = (char*)d_ws;
  __bf16* W1b = (__bf16*)ws;                                       // 512 KB
  __bf16* Vt  = (__bf16*)(ws + 512*1024);                          // 512 KB
  __bf16* w2p = (__bf16*)(ws + 512*1024 + 512*1024);               // 8 KB

  prep_kernel<<<298, 256, 0, stream>>>(W1, W2, gen, W1b, w2p, Vt);
  fused_kernel<<<256, 512, 0, stream>>>(xs, xe, W1b, b1, w2p, b2, scale, Vt,
                                        (float*)d_out);
}

// Round 17
// 126.972 us; speedup vs baseline: 2.0638x; 2.0348x over previous
//
#include <hip/hip_runtime.h>

typedef __bf16 bf16x8 __attribute__((ext_vector_type(8)));
typedef __bf16 bf16x4 __attribute__((ext_vector_type(4)));
typedef float f32x4 __attribute__((ext_vector_type(4)));

#define B_TOT   16384
#define DM      512
#define NF      64
#define KU      64   // K for final GEMM: 8 G + 36 sym pairs + 1 eye + 19 zero

#define MFMA16(a,b,c) __builtin_amdgcn_mfma_f32_16x16x32_bf16(a,b,c,0,0,0)

static __device__ __forceinline__ void gload_lds16(const void* g, void* l) {
  __builtin_amdgcn_global_load_lds((const __attribute__((address_space(1))) char*)g,
                                   (__attribute__((address_space(3))) char*)l, 16, 0, 0);
}

static __device__ __forceinline__ float fast_exp2(float x) {
  return __builtin_amdgcn_exp2f(x);
}
static __device__ __forceinline__ float fast_rcp(float x) {
  return __builtin_amdgcn_rcpf(x);
}

static __device__ __forceinline__ bf16x8 cvt8(f32x4 lo, f32x4 hi) {
  bf16x8 r;
  r[0]=(__bf16)lo[0]; r[1]=(__bf16)lo[1]; r[2]=(__bf16)lo[2]; r[3]=(__bf16)lo[3];
  r[4]=(__bf16)hi[0]; r[5]=(__bf16)hi[1]; r[6]=(__bf16)hi[2]; r[7]=(__bf16)hi[3];
  return r;
}

// ---------------- prep: W1->bf16, w2p pack, Vt build ---------------- (unchanged)
__global__ __launch_bounds__(256) void prep_kernel(const float* __restrict__ W1,
                                                   const float* __restrict__ W2,
                                                   const float* __restrict__ gen,
                                                   __bf16* __restrict__ W1b,
                                                   __bf16* __restrict__ w2p,
                                                   __bf16* __restrict__ Vt) {
  const int bid = blockIdx.x, tid = threadIdx.x;
  __shared__ float Ga[NF*NF];
  __shared__ float Gb[NF*NF];
  if (bid < 256) {
    const int i = (bid*256 + tid)*4;
    float4 v = *(const float4*)(W1 + i);
    bf16x4 o; o[0]=(__bf16)v.x; o[1]=(__bf16)v.y; o[2]=(__bf16)v.z; o[3]=(__bf16)v.w;
    *(bf16x4*)(W1b + i) = o;
  } else if (bid < 258) {
    const int n = (bid-256)*256 + tid;
    bf16x8 o;
    #pragma unroll
    for (int r = 0; r < 8; ++r) o[r] = (__bf16)W2[r*DM + n];
    *(bf16x8*)(w2p + n*8) = o;
  } else if (bid < 294) {
    const int p = bid - 258;
    int r = (p>=8)+(p>=15)+(p>=21)+(p>=26)+(p>=30)+(p>=33)+(p>=35);
    const int baser = r*8 - ((r*(r-1))>>1);
    const int s = r + p - baser;
    for (int i = tid; i < NF*NF; i += 256) {
      Ga[i] = gen[r*NF*NF + i];
      Gb[i] = gen[s*NF*NF + i];
    }
    __syncthreads();
    const int i  = tid >> 2;
    const int j0 = (tid & 3) * 16;
    float acc[16];
    #pragma unroll
    for (int jj = 0; jj < 16; ++jj) acc[jj] = 0.f;
    for (int k = 0; k < NF; ++k) {
      float a = Ga[i*NF + k];
      #pragma unroll
      for (int jj = 0; jj < 16; ++jj) acc[jj] += a * Gb[k*NF + j0 + jj];
    }
    if (r != s) {
      for (int k = 0; k < NF; ++k) {
        float a = Gb[i*NF + k];
        #pragma unroll
        for (int jj = 0; jj < 16; ++jj) acc[jj] += a * Ga[k*NF + j0 + jj];
      }
    }
    #pragma unroll
    for (int jj = 0; jj < 16; ++jj)
      Vt[(size_t)(i*NF + j0 + jj)*KU + 8 + p] = (__bf16)acc[jj];
  } else {
    const int q = bid - 294;
    #pragma unroll
    for (int v = 0; v < 4; ++v) {
      const int ij = q*1024 + tid*4 + v;
      bf16x8 g8;
      #pragma unroll
      for (int r = 0; r < 8; ++r) g8[r] = (__bf16)gen[r*NF*NF + ij];
      __bf16* row = Vt + (size_t)ij*KU;
      *(bf16x8*)row = g8;
      const float eye = ((ij >> 6) == (ij & 63)) ? 1.f : 0.f;
      bf16x4 e4; e4[0] = (__bf16)eye; e4[1] = (__bf16)0.f; e4[2] = (__bf16)0.f; e4[3] = (__bf16)0.f;
      *(bf16x4*)(row + 44) = e4;
      bf16x8 z8;
      #pragma unroll
      for (int k = 0; k < 8; ++k) z8[k] = (__bf16)0.f;
      *(bf16x8*)(row + 48) = z8;
      *(bf16x8*)(row + 56) = z8;
    }
  }
}

// ---------------- K1a: Gs = xs@W1^T + b1, Ge = xe@W1^T + b1 ----------------
// (R10's verified best) WG tile 64m x 512n, one mat per WG, grid 512; x read once.
__global__ __launch_bounds__(256, 2) void mlp1_kernel(
    const float* __restrict__ xs, const float* __restrict__ xe,
    const __bf16* __restrict__ W1b, const float* __restrict__ b1,
    __bf16* __restrict__ Gsb, __bf16* __restrict__ Geb) {
  const int bid = blockIdx.x;
  const int mat = bid & 1;
  const int mtile = bid >> 1;
  const int m0 = mtile*64;
  const float* __restrict__ X = mat ? xe : xs;
  __bf16* __restrict__ G = mat ? Geb : Gsb;

  __shared__ __bf16 As[2][64*64];   // 2 x 8 KB; chunk c of row at slot c^(row&7)
  __shared__ __bf16 Bs[512*64];     // 64 KB;   chunk c of row at slot c^((row>>3)&7)

  const int tid = threadIdx.x;
  const int l = tid & 63, w = tid >> 6;
  const int lc = l & 15, lg = l >> 4;

  const int arow = tid >> 2;      // 0..63
  const int aq   = tid & 3;
  const float* asrc = X + (size_t)(m0 + arow)*DM + aq*16;

  auto stageB = [&](int k0) {
    #pragma unroll
    for (int c = 0; c < 16; ++c) {
      const int row = c*32 + (tid >> 3);
      const int sp = (tid & 7) ^ ((row >> 3) & 7);
      gload_lds16(W1b + (size_t)row*DM + k0 + sp*8,
                  (char*)Bs + c*4096 + tid*16);
    }
  };

  f32x4 ar[4];
  auto loadA = [&](int k0) {
    const float* p = asrc + k0;
    ar[0] = *(const f32x4*)(p);
    ar[1] = *(const f32x4*)(p + 4);
    ar[2] = *(const f32x4*)(p + 8);
    ar[3] = *(const f32x4*)(p + 12);
  };
  auto writeA = [&](int buf) {
    const int e = arow & 7;
    *(bf16x8*)(&As[buf][0] + arow*64 + (((aq*2    ) ^ e)*8)) = cvt8(ar[0], ar[1]);
    *(bf16x8*)(&As[buf][0] + arow*64 + (((aq*2 + 1) ^ e)*8)) = cvt8(ar[2], ar[3]);
  };

  f32x4 acc[4][8];
  #pragma unroll
  for (int a = 0; a < 4; ++a)
    #pragma unroll
    for (int b = 0; b < 8; ++b) acc[a][b] = (f32x4)0.f;

  loadA(0);
  stageB(0);
  writeA(0);

  for (int ks = 0; ks < 8; ++ks) {
    const int cb = ks & 1, nb = cb ^ 1;
    __syncthreads();                 // sync1: staging(ks) visible (vmcnt+lgkm)
    if (ks < 7) loadA((ks+1)*64);    // HBM loads issue early, drain after compute
    #pragma unroll
    for (int kk = 0; kk < 2; ++kk) {
      bf16x8 aF[4], bF[8];
      #pragma unroll
      for (int mt = 0; mt < 4; ++mt) {
        const int row = mt*16 + lc;
        const int sp = (kk*4 + lg) ^ (row & 7);
        aF[mt] = *(const bf16x8*)(&As[cb][0] + row*64 + sp*8);
      }
      #pragma unroll
      for (int nt = 0; nt < 8; ++nt) {
        const int row = w*128 + lc*8 + nt;
        const int sp = (kk*4 + lg) ^ ((row >> 3) & 7);
        bF[nt] = *(const bf16x8*)(Bs + row*64 + sp*8);
      }
      #pragma unroll
      for (int mt = 0; mt < 4; ++mt)
        #pragma unroll
        for (int nt = 0; nt < 8; ++nt)
          acc[mt][nt] = MFMA16(aF[mt], bF[nt], acc[mt][nt]);
    }
    if (ks < 7) {
      __syncthreads();               // sync2: all Bs/As reads for ks done
      stageB((ks+1)*64);
      writeA(nb);
    }
  }

  // epilogue: +b1, cvt bf16, per-lane bf16x8 stores (n = w*128 + lc*8 .. +8)
  f32x4 b1lo = *(const f32x4*)(b1 + w*128 + lc*8);
  f32x4 b1hi = *(const f32x4*)(b1 + w*128 + lc*8 + 4);
  #pragma unroll
  for (int mt = 0; mt < 4; ++mt) {
    #pragma unroll
    for (int rg = 0; rg < 4; ++rg) {
      const int m = m0 + mt*16 + lg*4 + rg;
      bf16x8 o;
      #pragma unroll
      for (int nt = 0; nt < 8; ++nt) {
        const float bb = (nt < 4) ? b1lo[nt] : b1hi[nt-4];
        o[nt] = (__bf16)(acc[mt][nt][rg] + bb);
      }
      *(bf16x8*)(G + (size_t)m*DM + w*128 + lc*8) = o;
    }
  }
}

// ---------------- K1b: coefficients ---------------- (unchanged)
__global__ __launch_bounds__(256, 4) void coeff2_kernel(
    const __bf16* __restrict__ Gsb, const __bf16* __restrict__ Geb,
    const __bf16* __restrict__ w2p, const float* __restrict__ b2,
    const float* __restrict__ scale_p, __bf16* __restrict__ u) {
  const int tid = threadIdx.x;
  const int wv = tid >> 6, l = tid & 63;
  const int ls = l & 15;
  const int rib = wv*4 + (l >> 4);       // row in block, 0..15
  const int row = blockIdx.x*16 + rib;
  const size_t rb = (size_t)row * DM;

  __shared__ float cshr[16][8];

  float pz[4][8];
  #pragma unroll
  for (int st = 0; st < 4; ++st)
    #pragma unroll
    for (int r = 0; r < 8; ++r) pz[st][r] = 0.f;

  #pragma unroll
  for (int c = 0; c < 4; ++c) {
    const int nb = c*128 + ls*8;
    bf16x8 s8 = *(const bf16x8*)(Gsb + rb + nb);
    bf16x8 e8 = *(const bf16x8*)(Geb + rb + nb);
    #pragma unroll
    for (int i = 0; i < 8; ++i) {
      const float sv = (float)s8[i];
      const float dv = (float)e8[i] - sv;
      bf16x8 wv8 = *(const bf16x8*)(w2p + (size_t)(nb + i)*8);
      float w2f[8];
      #pragma unroll
      for (int r = 0; r < 8; ++r) w2f[r] = (float)wv8[r];
      #pragma unroll
      for (int st = 0; st < 4; ++st) {
        const float t = 0.125f + 0.25f*(float)st;
        const float mid = fmaf(t, dv, sv);
        const float g = mid * fast_rcp(1.f + fast_exp2(-2.4554669f * mid));
        #pragma unroll
        for (int r = 0; r < 8; ++r) pz[st][r] = fmaf(g, w2f[r], pz[st][r]);
      }
    }
  }

  #pragma unroll
  for (int st = 0; st < 4; ++st)
    #pragma unroll
    for (int r = 0; r < 8; ++r) {
      float v = pz[st][r];
      v += __shfl_xor(v, 1); v += __shfl_xor(v, 2);
      v += __shfl_xor(v, 4); v += __shfl_xor(v, 8);
      pz[st][r] = v;
    }

  const int rown = ls & 7;
  const float b2r = b2[rown];
  float sum = 0.f;
  #pragma unroll
  for (int st = 0; st < 4; ++st) {
    const float z = pz[st][rown] + b2r;
    const float te = fast_exp2(2.8853901f * z);   // e^(2z); inf-safe: tanh->1
    sum += 1.f - 2.f * fast_rcp(te + 1.f);
  }
  const float cs_own = sum * 0.25f * (*scale_p);  // * dt * scale
  if (ls < 8) cshr[rib][ls] = cs_own;
  __syncthreads();

  bf16x4 o;
  #pragma unroll
  for (int j = 0; j < 4; ++j) {
    const int k = ls*4 + j;
    float val;
    if (k < 8) {
      val = cshr[rib][k];
    } else if (k < 44) {
      const int p = k - 8;
      int r = (p>=8)+(p>=15)+(p>=21)+(p>=26)+(p>=30)+(p>=33)+(p>=35);
      const int baser = r*8 - ((r*(r-1))>>1);
      const int s2 = r + p - baser;
      val = 0.5f * cshr[rib][r] * cshr[rib][s2];
    } else if (k == 44) {
      val = 1.f;
    } else {
      val = 0.f;
    }
    o[j] = (__bf16)val;
  }
  *(bf16x4*)(u + (size_t)row*KU + ls*4) = o;
}

// ---------------- K3: out[b][ij] = sum_k u[b][k] * Vt[ij][k]  (K=64) ----------------
// R14 structure (LDS store-coalescing epilogue) + NONTEMPORAL final stores:
// nt-flagged global_store_dwordx4 bypasses L2 (no write-allocate, no u/Vt
// eviction). R13 measured 58% write peak vs fill's 87% with FETCH ~= 0 —
// L2 write-path overhead is the remaining candidate mechanism.
__global__ __launch_bounds__(256) void out_gemm_kernel(
    const __bf16* __restrict__ u, const __bf16* __restrict__ Vt,
    float* __restrict__ out) {
  __shared__ float Ls[16*256];   // 16 KB store-coalescing buffer
  const int bid = blockIdx.x;
  const int mb = bid >> 4, nbq = bid & 15;
  const int tid = threadIdx.x;
  const int l = tid & 63, wv = tid >> 6;
  const int lc = l & 15, lg = l >> 4;
  const int m0 = mb*64;
  const int n0 = nbq*256 + wv*64;

  f32x4 acc[4][4];
  #pragma unroll
  for (int a = 0; a < 4; ++a)
    #pragma unroll
    for (int b = 0; b < 4; ++b) acc[a][b] = (f32x4)0.f;

  #pragma unroll
  for (int ks = 0; ks < 2; ++ks) {
    const int k0 = ks*32 + lg*8;
    bf16x8 aF[4], bF[4];
    #pragma unroll
    for (int a = 0; a < 4; ++a)
      aF[a] = *(const bf16x8*)(u + (size_t)(m0 + a*16 + lc)*KU + k0);
    #pragma unroll
    for (int b = 0; b < 4; ++b)
      bF[b] = *(const bf16x8*)(Vt + (size_t)(n0 + lc*4 + b)*KU + k0);
    #pragma unroll
    for (int a = 0; a < 4; ++a)
      #pragma unroll
      for (int b = 0; b < 4; ++b)
        acc[a][b] = MFMA16(aF[a], bF[b], acc[a][b]);
  }

  #pragma unroll
  for (int a = 0; a < 4; ++a) {
    #pragma unroll
    for (int rg = 0; rg < 4; ++rg) {
      f32x4 o; o[0] = acc[a][0][rg]; o[1] = acc[a][1][rg];
      o[2] = acc[a][2][rg]; o[3] = acc[a][3][rg];
      *(f32x4*)(Ls + (lg*4 + rg)*256 + wv*64 + lc*4) = o;
    }
    __syncthreads();
    #pragma unroll
    for (int rr = 0; rr < 4; ++rr) {
      const int row = rr*4 + wv;
      f32x4 o = *(const f32x4*)(Ls + row*256 + l*4);
      __builtin_nontemporal_store(
          o, (f32x4*)(out + (size_t)(m0 + a*16 + row)*4096 + nbq*256 + l*4));
    }
    if (a < 3) __syncthreads();
  }
}

extern "C" void kernel_launch(void* const* d_in, const int* in_sizes, int n_in,
                              void* d_out, int out_size, void* d_ws, size_t ws_size,
                              hipStream_t stream) {
  const float* xs    = (const float*)d_in[0];
  const float* xe    = (const float*)d_in[1];
  const float* W1    = (const float*)d_in[2];
  const float* b1    = (const float*)d_in[3];
  const float* W2    = (const float*)d_in[4];
  const float* b2    = (const float*)d_in[5];
  const float* gen   = (const float*)d_in[6];
  const float* scale = (const float*)d_in[7];

  char* ws = (char*)d_ws;
  __bf16* W1b = (__bf16*)ws;                                    // 512 KB
  __bf16* u   = (__bf16*)(ws + 512*1024);                       // 2 MB
  __bf16* Vt  = (__bf16*)(ws + 512*1024 + 2*1024*1024);         // 512 KB
  __bf16* w2p = (__bf16*)(ws + 512*1024 + 2*1024*1024 + 512*1024); // 8 KB

  // Gs/Ge scratch lives in d_out (32 MB of 268), fully overwritten by K3.
  char* outc = (char*)d_out;
  __bf16* Gsb = (__bf16*)outc;
  __bf16* Geb = (__bf16*)(outc + (size_t)16*1024*1024);

  prep_kernel<<<298, 256, 0, stream>>>(W1, W2, gen, W1b, w2p, Vt);
  mlp1_kernel<<<512, 256, 0, stream>>>(xs, xe, W1b, b1, Gsb, Geb);
  coeff2_kernel<<<B_TOT/16, 256, 0, stream>>>(Gsb, Geb, w2p, b2, scale, u);
  out_gemm_kernel<<<256*16, 256, 0, stream>>>(u, Vt, (float*)d_out);
}

// Round 18
// 126.857 us; speedup vs baseline: 2.0657x; 1.0009x over previous
//
#include <hip/hip_runtime.h>

typedef __bf16 bf16x8 __attribute__((ext_vector_type(8)));
typedef __bf16 bf16x4 __attribute__((ext_vector_type(4)));
typedef float f32x4 __attribute__((ext_vector_type(4)));

#define B_TOT   16384
#define DM      512
#define NF      64
#define KU      64   // K for final GEMM: 8 G + 36 sym pairs + 1 eye + 19 zero

#define MFMA16(a,b,c) __builtin_amdgcn_mfma_f32_16x16x32_bf16(a,b,c,0,0,0)

static __device__ __forceinline__ void gload_lds16(const void* g, void* l) {
  __builtin_amdgcn_global_load_lds((const __attribute__((address_space(1))) char*)g,
                                   (__attribute__((address_space(3))) char*)l, 16, 0, 0);
}

static __device__ __forceinline__ float fast_exp2(float x) {
  return __builtin_amdgcn_exp2f(x);
}
static __device__ __forceinline__ float fast_rcp(float x) {
  return __builtin_amdgcn_rcpf(x);
}

static __device__ __forceinline__ bf16x8 cvt8(f32x4 lo, f32x4 hi) {
  bf16x8 r;
  r[0]=(__bf16)lo[0]; r[1]=(__bf16)lo[1]; r[2]=(__bf16)lo[2]; r[3]=(__bf16)lo[3];
  r[4]=(__bf16)hi[0]; r[5]=(__bf16)hi[1]; r[6]=(__bf16)hi[2]; r[7]=(__bf16)hi[3];
  return r;
}

// ---------------- prep: W1->bf16, w2p pack, Vt build ---------------- (unchanged)
__global__ __launch_bounds__(256) void prep_kernel(const float* __restrict__ W1,
                                                   const float* __restrict__ W2,
                                                   const float* __restrict__ gen,
                                                   __bf16* __restrict__ W1b,
                                                   __bf16* __restrict__ w2p,
                                                   __bf16* __restrict__ Vt) {
  const int bid = blockIdx.x, tid = threadIdx.x;
  __shared__ float Ga[NF*NF];
  __shared__ float Gb[NF*NF];
  if (bid < 256) {
    const int i = (bid*256 + tid)*4;
    float4 v = *(const float4*)(W1 + i);
    bf16x4 o; o[0]=(__bf16)v.x; o[1]=(__bf16)v.y; o[2]=(__bf16)v.z; o[3]=(__bf16)v.w;
    *(bf16x4*)(W1b + i) = o;
  } else if (bid < 258) {
    const int n = (bid-256)*256 + tid;
    bf16x8 o;
    #pragma unroll
    for (int r = 0; r < 8; ++r) o[r] = (__bf16)W2[r*DM + n];
    *(bf16x8*)(w2p + n*8) = o;
  } else if (bid < 294) {
    const int p = bid - 258;
    int r = (p>=8)+(p>=15)+(p>=21)+(p>=26)+(p>=30)+(p>=33)+(p>=35);
    const int baser = r*8 - ((r*(r-1))>>1);
    const int s = r + p - baser;
    for (int i = tid; i < NF*NF; i += 256) {
      Ga[i] = gen[r*NF*NF + i];
      Gb[i] = gen[s*NF*NF + i];
    }
    __syncthreads();
    const int i  = tid >> 2;
    const int j0 = (tid & 3) * 16;
    float acc[16];
    #pragma unroll
    for (int jj = 0; jj < 16; ++jj) acc[jj] = 0.f;
    for (int k = 0; k < NF; ++k) {
      float a = Ga[i*NF + k];
      #pragma unroll
      for (int jj = 0; jj < 16; ++jj) acc[jj] += a * Gb[k*NF + j0 + jj];
    }
    if (r != s) {
      for (int k = 0; k < NF; ++k) {
        float a = Gb[i*NF + k];
        #pragma unroll
        for (int jj = 0; jj < 16; ++jj) acc[jj] += a * Ga[k*NF + j0 + jj];
      }
    }
    #pragma unroll
    for (int jj = 0; jj < 16; ++jj)
      Vt[(size_t)(i*NF + j0 + jj)*KU + 8 + p] = (__bf16)acc[jj];
  } else {
    const int q = bid - 294;
    #pragma unroll
    for (int v = 0; v < 4; ++v) {
      const int ij = q*1024 + tid*4 + v;
      bf16x8 g8;
      #pragma unroll
      for (int r = 0; r < 8; ++r) g8[r] = (__bf16)gen[r*NF*NF + ij];
      __bf16* row = Vt + (size_t)ij*KU;
      *(bf16x8*)row = g8;
      const float eye = ((ij >> 6) == (ij & 63)) ? 1.f : 0.f;
      bf16x4 e4; e4[0] = (__bf16)eye; e4[1] = (__bf16)0.f; e4[2] = (__bf16)0.f; e4[3] = (__bf16)0.f;
      *(bf16x4*)(row + 44) = e4;
      bf16x8 z8;
      #pragma unroll
      for (int k = 0; k < 8; ++k) z8[k] = (__bf16)0.f;
      *(bf16x8*)(row + 48) = z8;
      *(bf16x8*)(row + 56) = z8;
    }
  }
}

// ---------------- K1a: Gs = xs@W1^T + b1, Ge = xe@W1^T + b1 ----------------
// (R10/R17 verified) WG tile 64m x 512n, one mat per WG, grid 512; x read once.
// NEW: G stores are NONTEMPORAL (stream-once data; keeps W1b/As/Bs lines in L2).
__global__ __launch_bounds__(256, 2) void mlp1_kernel(
    const float* __restrict__ xs, const float* __restrict__ xe,
    const __bf16* __restrict__ W1b, const float* __restrict__ b1,
    __bf16* __restrict__ Gsb, __bf16* __restrict__ Geb) {
  const int bid = blockIdx.x;
  const int mat = bid & 1;
  const int mtile = bid >> 1;
  const int m0 = mtile*64;
  const float* __restrict__ X = mat ? xe : xs;
  __bf16* __restrict__ G = mat ? Geb : Gsb;

  __shared__ __bf16 As[2][64*64];   // 2 x 8 KB; chunk c of row at slot c^(row&7)
  __shared__ __bf16 Bs[512*64];     // 64 KB;   chunk c of row at slot c^((row>>3)&7)

  const int tid = threadIdx.x;
  const int l = tid & 63, w = tid >> 6;
  const int lc = l & 15, lg = l >> 4;

  const int arow = tid >> 2;      // 0..63
  const int aq   = tid & 3;
  const float* asrc = X + (size_t)(m0 + arow)*DM + aq*16;

  auto stageB = [&](int k0) {
    #pragma unroll
    for (int c = 0; c < 16; ++c) {
      const int row = c*32 + (tid >> 3);
      const int sp = (tid & 7) ^ ((row >> 3) & 7);
      gload_lds16(W1b + (size_t)row*DM + k0 + sp*8,
                  (char*)Bs + c*4096 + tid*16);
    }
  };

  f32x4 ar[4];
  auto loadA = [&](int k0) {
    const float* p = asrc + k0;
    ar[0] = *(const f32x4*)(p);
    ar[1] = *(const f32x4*)(p + 4);
    ar[2] = *(const f32x4*)(p + 8);
    ar[3] = *(const f32x4*)(p + 12);
  };
  auto writeA = [&](int buf) {
    const int e = arow & 7;
    *(bf16x8*)(&As[buf][0] + arow*64 + (((aq*2    ) ^ e)*8)) = cvt8(ar[0], ar[1]);
    *(bf16x8*)(&As[buf][0] + arow*64 + (((aq*2 + 1) ^ e)*8)) = cvt8(ar[2], ar[3]);
  };

  f32x4 acc[4][8];
  #pragma unroll
  for (int a = 0; a < 4; ++a)
    #pragma unroll
    for (int b = 0; b < 8; ++b) acc[a][b] = (f32x4)0.f;

  loadA(0);
  stageB(0);
  writeA(0);

  for (int ks = 0; ks < 8; ++ks) {
    const int cb = ks & 1, nb = cb ^ 1;
    __syncthreads();                 // sync1: staging(ks) visible (vmcnt+lgkm)
    if (ks < 7) loadA((ks+1)*64);    // HBM loads issue early, drain after compute
    #pragma unroll
    for (int kk = 0; kk < 2; ++kk) {
      bf16x8 aF[4], bF[8];
      #pragma unroll
      for (int mt = 0; mt < 4; ++mt) {
        const int row = mt*16 + lc;
        const int sp = (kk*4 + lg) ^ (row & 7);
        aF[mt] = *(const bf16x8*)(&As[cb][0] + row*64 + sp*8);
      }
      #pragma unroll
      for (int nt = 0; nt < 8; ++nt) {
        const int row = w*128 + lc*8 + nt;
        const int sp = (kk*4 + lg) ^ ((row >> 3) & 7);
        bF[nt] = *(const bf16x8*)(Bs + row*64 + sp*8);
      }
      #pragma unroll
      for (int mt = 0; mt < 4; ++mt)
        #pragma unroll
        for (int nt = 0; nt < 8; ++nt)
          acc[mt][nt] = MFMA16(aF[mt], bF[nt], acc[mt][nt]);
    }
    if (ks < 7) {
      __syncthreads();               // sync2: all Bs/As reads for ks done
      stageB((ks+1)*64);
      writeA(nb);
    }
  }

  // epilogue: +b1, cvt bf16, NONTEMPORAL per-lane bf16x8 stores
  f32x4 b1lo = *(const f32x4*)(b1 + w*128 + lc*8);
  f32x4 b1hi = *(const f32x4*)(b1 + w*128 + lc*8 + 4);
  #pragma unroll
  for (int mt = 0; mt < 4; ++mt) {
    #pragma unroll
    for (int rg = 0; rg < 4; ++rg) {
      const int m = m0 + mt*16 + lg*4 + rg;
      bf16x8 o;
      #pragma unroll
      for (int nt = 0; nt < 8; ++nt) {
        const float bb = (nt < 4) ? b1lo[nt] : b1hi[nt-4];
        o[nt] = (__bf16)(acc[mt][nt][rg] + bb);
      }
      __builtin_nontemporal_store(o, (bf16x8*)(G + (size_t)m*DM + w*128 + lc*8));
    }
  }
}

// ---------------- K1b: coefficients ----------------
// (unchanged math; Gs/Ge reads are NONTEMPORAL — stream-once data)
__global__ __launch_bounds__(256, 4) void coeff2_kernel(
    const __bf16* __restrict__ Gsb, const __bf16* __restrict__ Geb,
    const __bf16* __restrict__ w2p, const float* __restrict__ b2,
    const float* __restrict__ scale_p, __bf16* __restrict__ u) {
  const int tid = threadIdx.x;
  const int wv = tid >> 6, l = tid & 63;
  const int ls = l & 15;
  const int rib = wv*4 + (l >> 4);       // row in block, 0..15
  const int row = blockIdx.x*16 + rib;
  const size_t rb = (size_t)row * DM;

  __shared__ float cshr[16][8];

  float pz[4][8];
  #pragma unroll
  for (int st = 0; st < 4; ++st)
    #pragma unroll
    for (int r = 0; r < 8; ++r) pz[st][r] = 0.f;

  #pragma unroll
  for (int c = 0; c < 4; ++c) {
    const int nb = c*128 + ls*8;
    bf16x8 s8 = __builtin_nontemporal_load((const bf16x8*)(Gsb + rb + nb));
    bf16x8 e8 = __builtin_nontemporal_load((const bf16x8*)(Geb + rb + nb));
    #pragma unroll
    for (int i = 0; i < 8; ++i) {
      const float sv = (float)s8[i];
      const float dv = (float)e8[i] - sv;
      bf16x8 wv8 = *(const bf16x8*)(w2p + (size_t)(nb + i)*8);
      float w2f[8];
      #pragma unroll
      for (int r = 0; r < 8; ++r) w2f[r] = (float)wv8[r];
      #pragma unroll
      for (int st = 0; st < 4; ++st) {
        const float t = 0.125f + 0.25f*(float)st;
        const float mid = fmaf(t, dv, sv);
        const float g = mid * fast_rcp(1.f + fast_exp2(-2.4554669f * mid));
        #pragma unroll
        for (int r = 0; r < 8; ++r) pz[st][r] = fmaf(g, w2f[r], pz[st][r]);
      }
    }
  }

  #pragma unroll
  for (int st = 0; st < 4; ++st)
    #pragma unroll
    for (int r = 0; r < 8; ++r) {
      float v = pz[st][r];
      v += __shfl_xor(v, 1); v += __shfl_xor(v, 2);
      v += __shfl_xor(v, 4); v += __shfl_xor(v, 8);
      pz[st][r] = v;
    }

  const int rown = ls & 7;
  const float b2r = b2[rown];
  float sum = 0.f;
  #pragma unroll
  for (int st = 0; st < 4; ++st) {
    const float z = pz[st][rown] + b2r;
    const float te = fast_exp2(2.8853901f * z);   // e^(2z); inf-safe: tanh->1
    sum += 1.f - 2.f * fast_rcp(te + 1.f);
  }
  const float cs_own = sum * 0.25f * (*scale_p);  // * dt * scale
  if (ls < 8) cshr[rib][ls] = cs_own;
  __syncthreads();

  bf16x4 o;
  #pragma unroll
  for (int j = 0; j < 4; ++j) {
    const int k = ls*4 + j;
    float val;
    if (k < 8) {
      val = cshr[rib][k];
    } else if (k < 44) {
      const int p = k - 8;
      int r = (p>=8)+(p>=15)+(p>=21)+(p>=26)+(p>=30)+(p>=33)+(p>=35);
      const int baser = r*8 - ((r*(r-1))>>1);
      const int s2 = r + p - baser;
      val = 0.5f * cshr[rib][r] * cshr[rib][s2];
    } else if (k == 44) {
      val = 1.f;
    } else {
      val = 0.f;
    }
    o[j] = (__bf16)val;
  }
  *(bf16x4*)(u + (size_t)row*KU + ls*4) = o;
}

// ---------------- K3: out[b][ij] = sum_k u[b][k] * Vt[ij][k]  (K=64) ----------------
// (R17 verified: LDS store-coalescing + NONTEMPORAL stores; ~6.4 TB/s write)
__global__ __launch_bounds__(256) void out_gemm_kernel(
    const __bf16* __restrict__ u, const __bf16* __restrict__ Vt,
    float* __restrict__ out) {
  __shared__ float Ls[16*256];   // 16 KB store-coalescing buffer
  const int bid = blockIdx.x;
  const int mb = bid >> 4, nbq = bid & 15;
  const int tid = threadIdx.x;
  const int l = tid & 63, wv = tid >> 6;
  const int lc = l & 15, lg = l >> 4;
  const int m0 = mb*64;
  const int n0 = nbq*256 + wv*64;

  f32x4 acc[4][4];
  #pragma unroll
  for (int a = 0; a < 4; ++a)
    #pragma unroll
    for (int b = 0; b < 4; ++b) acc[a][b] = (f32x4)0.f;

  #pragma unroll
  for (int ks = 0; ks < 2; ++ks) {
    const int k0 = ks*32 + lg*8;
    bf16x8 aF[4], bF[4];
    #pragma unroll
    for (int a = 0; a < 4; ++a)
      aF[a] = *(const bf16x8*)(u + (size_t)(m0 + a*16 + lc)*KU + k0);
    #pragma unroll
    for (int b = 0; b < 4; ++b)
      bF[b] = *(const bf16x8*)(Vt + (size_t)(n0 + lc*4 + b)*KU + k0);
    #pragma unroll
    for (int a = 0; a < 4; ++a)
      #pragma unroll
      for (int b = 0; b < 4; ++b)
        acc[a][b] = MFMA16(aF[a], bF[b], acc[a][b]);
  }

  #pragma unroll
  for (int a = 0; a < 4; ++a) {
    #pragma unroll
    for (int rg = 0; rg < 4; ++rg) {
      f32x4 o; o[0] = acc[a][0][rg]; o[1] = acc[a][1][rg];
      o[2] = acc[a][2][rg]; o[3] = acc[a][3][rg];
      *(f32x4*)(Ls + (lg*4 + rg)*256 + wv*64 + lc*4) = o;
    }
    __syncthreads();
    #pragma unroll
    for (int rr = 0; rr < 4; ++rr) {
      const int row = rr*4 + wv;
      f32x4 o = *(const f32x4*)(Ls + row*256 + l*4);
      __builtin_nontemporal_store(
          o, (f32x4*)(out + (size_t)(m0 + a*16 + row)*4096 + nbq*256 + l*4));
    }
    if (a < 3) __syncthreads();
  }
}

extern "C" void kernel_launch(void* const* d_in, const int* in_sizes, int n_in,
                              void* d_out, int out_size, void* d_ws, size_t ws_size,
                              hipStream_t stream) {
  const float* xs    = (const float*)d_in[0];
  const float* xe    = (const float*)d_in[1];
  const float* W1    = (const float*)d_in[2];
  const float* b1    = (const float*)d_in[3];
  const float* W2    = (const float*)d_in[4];
  const float* b2    = (const float*)d_in[5];
  const float* gen   = (const float*)d_in[6];
  const float* scale = (const float*)d_in[7];

  char* ws = (char*)d_ws;
  __bf16* W1b = (__bf16*)ws;                                    // 512 KB
  __bf16* u   = (__bf16*)(ws + 512*1024);                       // 2 MB
  __bf16* Vt  = (__bf16*)(ws + 512*1024 + 2*1024*1024);         // 512 KB
  __bf16* w2p = (__bf16*)(ws + 512*1024 + 2*1024*1024 + 512*1024); // 8 KB

  // Gs/Ge scratch lives in d_out (32 MB of 268), fully overwritten by K3.
  char* outc = (char*)d_out;
  __bf16* Gsb = (__bf16*)outc;
  __bf16* Geb = (__bf16*)(outc + (size_t)16*1024*1024);

  prep_kernel<<<298, 256, 0, stream>>>(W1, W2, gen, W1b, w2p, Vt);
  mlp1_kernel<<<512, 256, 0, stream>>>(xs, xe, W1b, b1, Gsb, Geb);
  coeff2_kernel<<<B_TOT/16, 256, 0, stream>>>(Gsb, Geb, w2p, b2, scale, u);
  out_gemm_kernel<<<256*16, 256, 0, stream>>>(u, Vt, (float*)d_out);
}

// Round 19
// 125.542 us; speedup vs baseline: 2.0873x; 1.0105x over previous
//
#include <hip/hip_runtime.h>

typedef __bf16 bf16x8 __attribute__((ext_vector_type(8)));
typedef __bf16 bf16x4 __attribute__((ext_vector_type(4)));
typedef float f32x4 __attribute__((ext_vector_type(4)));

#define B_TOT   16384
#define DM      512
#define NF      64
#define KU      64   // K for final GEMM: 8 G + 36 sym pairs + 1 eye + 19 zero

#define MFMA16(a,b,c) __builtin_amdgcn_mfma_f32_16x16x32_bf16(a,b,c,0,0,0)

static __device__ __forceinline__ void gload_lds16(const void* g, void* l) {
  __builtin_amdgcn_global_load_lds((const __attribute__((address_space(1))) char*)g,
                                   (__attribute__((address_space(3))) char*)l, 16, 0, 0);
}

static __device__ __forceinline__ float fast_exp2(float x) {
  return __builtin_amdgcn_exp2f(x);
}
static __device__ __forceinline__ float fast_rcp(float x) {
  return __builtin_amdgcn_rcpf(x);
}

static __device__ __forceinline__ bf16x8 cvt8(f32x4 lo, f32x4 hi) {
  bf16x8 r;
  r[0]=(__bf16)lo[0]; r[1]=(__bf16)lo[1]; r[2]=(__bf16)lo[2]; r[3]=(__bf16)lo[3];
  r[4]=(__bf16)hi[0]; r[5]=(__bf16)hi[1]; r[6]=(__bf16)hi[2]; r[7]=(__bf16)hi[3];
  return r;
}

// ---------------- prep: W1->bf16, w2p pack, Vt build ---------------- (unchanged)
__global__ __launch_bounds__(256) void prep_kernel(const float* __restrict__ W1,
                                                   const float* __restrict__ W2,
                                                   const float* __restrict__ gen,
                                                   __bf16* __restrict__ W1b,
                                                   __bf16* __restrict__ w2p,
                                                   __bf16* __restrict__ Vt) {
  const int bid = blockIdx.x, tid = threadIdx.x;
  __shared__ float Ga[NF*NF];
  __shared__ float Gb[NF*NF];
  if (bid < 256) {
    const int i = (bid*256 + tid)*4;
    float4 v = *(const float4*)(W1 + i);
    bf16x4 o; o[0]=(__bf16)v.x; o[1]=(__bf16)v.y; o[2]=(__bf16)v.z; o[3]=(__bf16)v.w;
    *(bf16x4*)(W1b + i) = o;
  } else if (bid < 258) {
    const int n = (bid-256)*256 + tid;
    bf16x8 o;
    #pragma unroll
    for (int r = 0; r < 8; ++r) o[r] = (__bf16)W2[r*DM + n];
    *(bf16x8*)(w2p + n*8) = o;
  } else if (bid < 294) {
    const int p = bid - 258;
    int r = (p>=8)+(p>=15)+(p>=21)+(p>=26)+(p>=30)+(p>=33)+(p>=35);
    const int baser = r*8 - ((r*(r-1))>>1);
    const int s = r + p - baser;
    for (int i = tid; i < NF*NF; i += 256) {
      Ga[i] = gen[r*NF*NF + i];
      Gb[i] = gen[s*NF*NF + i];
    }
    __syncthreads();
    const int i  = tid >> 2;
    const int j0 = (tid & 3) * 16;
    float acc[16];
    #pragma unroll
    for (int jj = 0; jj < 16; ++jj) acc[jj] = 0.f;
    for (int k = 0; k < NF; ++k) {
      float a = Ga[i*NF + k];
      #pragma unroll
      for (int jj = 0; jj < 16; ++jj) acc[jj] += a * Gb[k*NF + j0 + jj];
    }
    if (r != s) {
      for (int k = 0; k < NF; ++k) {
        float a = Gb[i*NF + k];
        #pragma unroll
        for (int jj = 0; jj < 16; ++jj) acc[jj] += a * Ga[k*NF + j0 + jj];
      }
    }
    #pragma unroll
    for (int jj = 0; jj < 16; ++jj)
      Vt[(size_t)(i*NF + j0 + jj)*KU + 8 + p] = (__bf16)acc[jj];
  } else {
    const int q = bid - 294;
    #pragma unroll
    for (int v = 0; v < 4; ++v) {
      const int ij = q*1024 + tid*4 + v;
      bf16x8 g8;
      #pragma unroll
      for (int r = 0; r < 8; ++r) g8[r] = (__bf16)gen[r*NF*NF + ij];
      __bf16* row = Vt + (size_t)ij*KU;
      *(bf16x8*)row = g8;
      const float eye = ((ij >> 6) == (ij & 63)) ? 1.f : 0.f;
      bf16x4 e4; e4[0] = (__bf16)eye; e4[1] = (__bf16)0.f; e4[2] = (__bf16)0.f; e4[3] = (__bf16)0.f;
      *(bf16x4*)(row + 44) = e4;
      bf16x8 z8;
      #pragma unroll
      for (int k = 0; k < 8; ++k) z8[k] = (__bf16)0.f;
      *(bf16x8*)(row + 48) = z8;
      *(bf16x8*)(row + 56) = z8;
    }
  }
}

// ---------------- K1a: Gs = xs@W1^T + b1, Ge = xe@W1^T + b1 ----------------
// R10 dataflow, now 512 threads / 8 WAVES per WG (same 64m x 512n tile, same
// LDS bytes: As 2x8KB + Bs 64KB = 80KB -> 2 WG/CU = 16 waves/CU, 2x latency
// hiding vs R10's 8). Wave w owns n-strip [w*64, w*64+64): acc[4][4] (64 VGPR).
// B-rows permuted within strip: frag nt, lane lc <- row w*64 + lc*4 + nt
// => per-lane bf16x4 G-stores (128B contiguous per wave-instr per row).
// Per-element K-accumulation order identical to R10 => bit-identical G.
__global__ __launch_bounds__(512, 4) void mlp1_kernel(
    const float* __restrict__ xs, const float* __restrict__ xe,
    const __bf16* __restrict__ W1b, const float* __restrict__ b1,
    __bf16* __restrict__ Gsb, __bf16* __restrict__ Geb) {
  const int bid = blockIdx.x;
  const int mat = bid & 1;
  const int mtile = bid >> 1;
  const int m0 = mtile*64;
  const float* __restrict__ X = mat ? xe : xs;
  __bf16* __restrict__ G = mat ? Geb : Gsb;

  __shared__ __bf16 As[2][64*64];   // 2 x 8 KB; chunk c of row at slot c^(row&7)
  __shared__ __bf16 Bs[512*64];     // 64 KB;   chunk c of row at slot c^((row>>3)&7)

  const int tid = threadIdx.x;
  const int l = tid & 63, w = tid >> 6;   // 8 waves
  const int lc = l & 15, lg = l >> 4;

  // ---- A staging: thread -> row tid>>3 (0..63), chunk aq=tid&7 (8 floats)
  const int arow = tid >> 3;
  const int aq   = tid & 7;
  const float* asrc = X + (size_t)(m0 + arow)*DM + aq*8;

  auto stageB = [&](int k0) {
    #pragma unroll
    for (int c = 0; c < 8; ++c) {
      const int row = c*64 + (tid >> 3);
      const int sp = (tid & 7) ^ ((row >> 3) & 7);
      gload_lds16(W1b + (size_t)row*DM + k0 + sp*8,
                  (char*)Bs + c*8192 + tid*16);
    }
  };

  f32x4 ar0, ar1;
  auto loadA = [&](int k0) {
    const float* p = asrc + k0;
    ar0 = *(const f32x4*)(p);
    ar1 = *(const f32x4*)(p + 4);
  };
  auto writeA = [&](int buf) {
    const int e = arow & 7;
    *(bf16x8*)(&As[buf][0] + arow*64 + ((aq ^ e)*8)) = cvt8(ar0, ar1);
  };

  f32x4 acc[4][4];
  #pragma unroll
  for (int a = 0; a < 4; ++a)
    #pragma unroll
    for (int b = 0; b < 4; ++b) acc[a][b] = (f32x4)0.f;

  loadA(0);
  stageB(0);
  writeA(0);

  for (int ks = 0; ks < 8; ++ks) {
    const int cb = ks & 1, nb = cb ^ 1;
    __syncthreads();                 // sync1: staging(ks) visible (vmcnt+lgkm)
    if (ks < 7) loadA((ks+1)*64);    // HBM loads issue early, drain after compute
    #pragma unroll
    for (int kk = 0; kk < 2; ++kk) {
      bf16x8 aF[4], bF[4];
      #pragma unroll
      for (int mt = 0; mt < 4; ++mt) {
        const int row = mt*16 + lc;
        const int sp = (kk*4 + lg) ^ (row & 7);
        aF[mt] = *(const bf16x8*)(&As[cb][0] + row*64 + sp*8);
      }
      #pragma unroll
      for (int nt = 0; nt < 4; ++nt) {
        const int row = w*64 + lc*4 + nt;
        const int sp = (kk*4 + lg) ^ ((row >> 3) & 7);
        bF[nt] = *(const bf16x8*)(Bs + row*64 + sp*8);
      }
      #pragma unroll
      for (int mt = 0; mt < 4; ++mt)
        #pragma unroll
        for (int nt = 0; nt < 4; ++nt)
          acc[mt][nt] = MFMA16(aF[mt], bF[nt], acc[mt][nt]);
    }
    if (ks < 7) {
      __syncthreads();               // sync2: all Bs/As reads for ks done
      stageB((ks+1)*64);
      writeA(nb);
    }
  }

  // epilogue: +b1, cvt bf16, NONTEMPORAL per-lane bf16x4 stores (n = w*64+lc*4..+4)
  f32x4 b1v = *(const f32x4*)(b1 + w*64 + lc*4);
  #pragma unroll
  for (int mt = 0; mt < 4; ++mt) {
    #pragma unroll
    for (int rg = 0; rg < 4; ++rg) {
      const int m = m0 + mt*16 + lg*4 + rg;
      bf16x4 o;
      #pragma unroll
      for (int nt = 0; nt < 4; ++nt) o[nt] = (__bf16)(acc[mt][nt][rg] + b1v[nt]);
      __builtin_nontemporal_store(o, (bf16x4*)(G + (size_t)m*DM + w*64 + lc*4));
    }
  }
}

// ---------------- K1b: coefficients ---------------- (unchanged from R18)
__global__ __launch_bounds__(256, 4) void coeff2_kernel(
    const __bf16* __restrict__ Gsb, const __bf16* __restrict__ Geb,
    const __bf16* __restrict__ w2p, const float* __restrict__ b2,
    const float* __restrict__ scale_p, __bf16* __restrict__ u) {
  const int tid = threadIdx.x;
  const int wv = tid >> 6, l = tid & 63;
  const int ls = l & 15;
  const int rib = wv*4 + (l >> 4);       // row in block, 0..15
  const int row = blockIdx.x*16 + rib;
  const size_t rb = (size_t)row * DM;

  __shared__ float cshr[16][8];

  float pz[4][8];
  #pragma unroll
  for (int st = 0; st < 4; ++st)
    #pragma unroll
    for (int r = 0; r < 8; ++r) pz[st][r] = 0.f;

  #pragma unroll
  for (int c = 0; c < 4; ++c) {
    const int nb = c*128 + ls*8;
    bf16x8 s8 = __builtin_nontemporal_load((const bf16x8*)(Gsb + rb + nb));
    bf16x8 e8 = __builtin_nontemporal_load((const bf16x8*)(Geb + rb + nb));
    #pragma unroll
    for (int i = 0; i < 8; ++i) {
      const float sv = (float)s8[i];
      const float dv = (float)e8[i] - sv;
      bf16x8 wv8 = *(const bf16x8*)(w2p + (size_t)(nb + i)*8);
      float w2f[8];
      #pragma unroll
      for (int r = 0; r < 8; ++r) w2f[r] = (float)wv8[r];
      #pragma unroll
      for (int st = 0; st < 4; ++st) {
        const float t = 0.125f + 0.25f*(float)st;
        const float mid = fmaf(t, dv, sv);
        const float g = mid * fast_rcp(1.f + fast_exp2(-2.4554669f * mid));
        #pragma unroll
        for (int r = 0; r < 8; ++r) pz[st][r] = fmaf(g, w2f[r], pz[st][r]);
      }
    }
  }

  #pragma unroll
  for (int st = 0; st < 4; ++st)
    #pragma unroll
    for (int r = 0; r < 8; ++r) {
      float v = pz[st][r];
      v += __shfl_xor(v, 1); v += __shfl_xor(v, 2);
      v += __shfl_xor(v, 4); v += __shfl_xor(v, 8);
      pz[st][r] = v;
    }

  const int rown = ls & 7;
  const float b2r = b2[rown];
  float sum = 0.f;
  #pragma unroll
  for (int st = 0; st < 4; ++st) {
    const float z = pz[st][rown] + b2r;
    const float te = fast_exp2(2.8853901f * z);   // e^(2z); inf-safe: tanh->1
    sum += 1.f - 2.f * fast_rcp(te + 1.f);
  }
  const float cs_own = sum * 0.25f * (*scale_p);  // * dt * scale
  if (ls < 8) cshr[rib][ls] = cs_own;
  __syncthreads();

  bf16x4 o;
  #pragma unroll
  for (int j = 0; j < 4; ++j) {
    const int k = ls*4 + j;
    float val;
    if (k < 8) {
      val = cshr[rib][k];
    } else if (k < 44) {
      const int p = k - 8;
      int r = (p>=8)+(p>=15)+(p>=21)+(p>=26)+(p>=30)+(p>=33)+(p>=35);
      const int baser = r*8 - ((r*(r-1))>>1);
      const int s2 = r + p - baser;
      val = 0.5f * cshr[rib][r] * cshr[rib][s2];
    } else if (k == 44) {
      val = 1.f;
    } else {
      val = 0.f;
    }
    o[j] = (__bf16)val;
  }
  *(bf16x4*)(u + (size_t)row*KU + ls*4) = o;
}

// ---------------- K3: out[b][ij] = sum_k u[b][k] * Vt[ij][k]  (K=64) ----------------
// (R17 verified: LDS store-coalescing + NONTEMPORAL stores; ~6.4 TB/s write)
__global__ __launch_bounds__(256) void out_gemm_kernel(
    const __bf16* __restrict__ u, const __bf16* __restrict__ Vt,
    float* __restrict__ out) {
  __shared__ float Ls[16*256];   // 16 KB store-coalescing buffer
  const int bid = blockIdx.x;
  const int mb = bid >> 4, nbq = bid & 15;
  const int tid = threadIdx.x;
  const int l = tid & 63, wv = tid >> 6;
  const int lc = l & 15, lg = l >> 4;
  const int m0 = mb*64;
  const int n0 = nbq*256 + wv*64;

  f32x4 acc[4][4];
  #pragma unroll
  for (int a = 0; a < 4; ++a)
    #pragma unroll
    for (int b = 0; b < 4; ++b) acc[a][b] = (f32x4)0.f;

  #pragma unroll
  for (int ks = 0; ks < 2; ++ks) {
    const int k0 = ks*32 + lg*8;
    bf16x8 aF[4], bF[4];
    #pragma unroll
    for (int a = 0; a < 4; ++a)
      aF[a] = *(const bf16x8*)(u + (size_t)(m0 + a*16 + lc)*KU + k0);
    #pragma unroll
    for (int b = 0; b < 4; ++b)
      bF[b] = *(const bf16x8*)(Vt + (size_t)(n0 + lc*4 + b)*KU + k0);
    #pragma unroll
    for (int a = 0; a < 4; ++a)
      #pragma unroll
      for (int b = 0; b < 4; ++b)
        acc[a][b] = MFMA16(aF[a], bF[b], acc[a][b]);
  }

  #pragma unroll
  for (int a = 0; a < 4; ++a) {
    #pragma unroll
    for (int rg = 0; rg < 4; ++rg) {
      f32x4 o; o[0] = acc[a][0][rg]; o[1] = acc[a][1][rg];
      o[2] = acc[a][2][rg]; o[3] = acc[a][3][rg];
      *(f32x4*)(Ls + (lg*4 + rg)*256 + wv*64 + lc*4) = o;
    }
    __syncthreads();
    #pragma unroll
    for (int rr = 0; rr < 4; ++rr) {
      const int row = rr*4 + wv;
      f32x4 o = *(const f32x4*)(Ls + row*256 + l*4);
      __builtin_nontemporal_store(
          o, (f32x4*)(out + (size_t)(m0 + a*16 + row)*4096 + nbq*256 + l*4));
    }
    if (a < 3) __syncthreads();
  }
}

extern "C" void kernel_launch(void* const* d_in, const int* in_sizes, int n_in,
                              void* d_out, int out_size, void* d_ws, size_t ws_size,
                              hipStream_t stream) {
  const float* xs    = (const float*)d_in[0];
  const float* xe    = (const float*)d_in[1];
  const float* W1    = (const float*)d_in[2];
  const float* b1    = (const float*)d_in[3];
  const float* W2    = (const float*)d_in[4];
  const float* b2    = (const float*)d_in[5];
  const float* gen   = (const float*)d_in[6];
  const float* scale = (const float*)d_in[7];

  char* ws = (char*)d_ws;
  __bf16* W1b = (__bf16*)ws;                                    // 512 KB
  __bf16* u   = (__bf16*)(ws + 512*1024);                       // 2 MB
  __bf16* Vt  = (__bf16*)(ws + 512*1024 + 2*1024*1024);         // 512 KB
  __bf16* w2p = (__bf16*)(ws + 512*1024 + 2*1024*1024 + 512*1024); // 8 KB

  // Gs/Ge scratch lives in d_out (32 MB of 268), fully overwritten by K3.
  char* outc = (char*)d_out;
  __bf16* Gsb = (__bf16*)outc;
  __bf16* Geb = (__bf16*)(outc + (size_t)16*1024*1024);

  prep_kernel<<<298, 256, 0, stream>>>(W1, W2, gen, W1b, w2p, Vt);
  mlp1_kernel<<<512, 512, 0, stream>>>(xs, xe, W1b, b1, Gsb, Geb);
  coeff2_kernel<<<B_TOT/16, 256, 0, stream>>>(Gsb, Geb, w2p, b2, scale, u);
  out_gemm_kernel<<<256*16, 256, 0, stream>>>(u, Vt, (float*)d_out);
}

// Round 20
// 125.322 us; speedup vs baseline: 2.0910x; 1.0018x over previous
//
#include <hip/hip_runtime.h>

typedef __bf16 bf16x8 __attribute__((ext_vector_type(8)));
typedef __bf16 bf16x4 __attribute__((ext_vector_type(4)));
typedef float f32x4 __attribute__((ext_vector_type(4)));

#define B_TOT   16384
#define DM      512
#define NF      64
#define KU      64   // K for final GEMM: 8 G + 36 sym pairs + 1 eye + 19 zero

#define MFMA16(a,b,c) __builtin_amdgcn_mfma_f32_16x16x32_bf16(a,b,c,0,0,0)

static __device__ __forceinline__ void gload_lds16(const void* g, void* l) {
  __builtin_amdgcn_global_load_lds((const __attribute__((address_space(1))) char*)g,
                                   (__attribute__((address_space(3))) char*)l, 16, 0, 0);
}

static __device__ __forceinline__ float fast_exp2(float x) {
  return __builtin_amdgcn_exp2f(x);
}
static __device__ __forceinline__ float fast_rcp(float x) {
  return __builtin_amdgcn_rcpf(x);
}

static __device__ __forceinline__ bf16x8 cvt8(f32x4 lo, f32x4 hi) {
  bf16x8 r;
  r[0]=(__bf16)lo[0]; r[1]=(__bf16)lo[1]; r[2]=(__bf16)lo[2]; r[3]=(__bf16)lo[3];
  r[4]=(__bf16)hi[0]; r[5]=(__bf16)hi[1]; r[6]=(__bf16)hi[2]; r[7]=(__bf16)hi[3];
  return r;
}

// ---------------- prep: W1->bf16, w2p pack, Vt build ---------------- (unchanged)
__global__ __launch_bounds__(256) void prep_kernel(const float* __restrict__ W1,
                                                   const float* __restrict__ W2,
                                                   const float* __restrict__ gen,
                                                   __bf16* __restrict__ W1b,
                                                   __bf16* __restrict__ w2p,
                                                   __bf16* __restrict__ Vt) {
  const int bid = blockIdx.x, tid = threadIdx.x;
  __shared__ float Ga[NF*NF];
  __shared__ float Gb[NF*NF];
  if (bid < 256) {
    const int i = (bid*256 + tid)*4;
    float4 v = *(const float4*)(W1 + i);
    bf16x4 o; o[0]=(__bf16)v.x; o[1]=(__bf16)v.y; o[2]=(__bf16)v.z; o[3]=(__bf16)v.w;
    *(bf16x4*)(W1b + i) = o;
  } else if (bid < 258) {
    const int n = (bid-256)*256 + tid;
    bf16x8 o;
    #pragma unroll
    for (int r = 0; r < 8; ++r) o[r] = (__bf16)W2[r*DM + n];
    *(bf16x8*)(w2p + n*8) = o;
  } else if (bid < 294) {
    const int p = bid - 258;
    int r = (p>=8)+(p>=15)+(p>=21)+(p>=26)+(p>=30)+(p>=33)+(p>=35);
    const int baser = r*8 - ((r*(r-1))>>1);
    const int s = r + p - baser;
    for (int i = tid; i < NF*NF; i += 256) {
      Ga[i] = gen[r*NF*NF + i];
      Gb[i] = gen[s*NF*NF + i];
    }
    __syncthreads();
    const int i  = tid >> 2;
    const int j0 = (tid & 3) * 16;
    float acc[16];
    #pragma unroll
    for (int jj = 0; jj < 16; ++jj) acc[jj] = 0.f;
    for (int k = 0; k < NF; ++k) {
      float a = Ga[i*NF + k];
      #pragma unroll
      for (int jj = 0; jj < 16; ++jj) acc[jj] += a * Gb[k*NF + j0 + jj];
    }
    if (r != s) {
      for (int k = 0; k < NF; ++k) {
        float a = Gb[i*NF + k];
        #pragma unroll
        for (int jj = 0; jj < 16; ++jj) acc[jj] += a * Ga[k*NF + j0 + jj];
      }
    }
    #pragma unroll
    for (int jj = 0; jj < 16; ++jj)
      Vt[(size_t)(i*NF + j0 + jj)*KU + 8 + p] = (__bf16)acc[jj];
  } else {
    const int q = bid - 294;
    #pragma unroll
    for (int v = 0; v < 4; ++v) {
      const int ij = q*1024 + tid*4 + v;
      bf16x8 g8;
      #pragma unroll
      for (int r = 0; r < 8; ++r) g8[r] = (__bf16)gen[r*NF*NF + ij];
      __bf16* row = Vt + (size_t)ij*KU;
      *(bf16x8*)row = g8;
      const float eye = ((ij >> 6) == (ij & 63)) ? 1.f : 0.f;
      bf16x4 e4; e4[0] = (__bf16)eye; e4[1] = (__bf16)0.f; e4[2] = (__bf16)0.f; e4[3] = (__bf16)0.f;
      *(bf16x4*)(row + 44) = e4;
      bf16x8 z8;
      #pragma unroll
      for (int k = 0; k < 8; ++k) z8[k] = (__bf16)0.f;
      *(bf16x8*)(row + 48) = z8;
      *(bf16x8*)(row + 56) = z8;
    }
  }
}

// ---------------- mlpc2: fused MLP + coefficients ----------------
// One WG = 32 batch rows, BOTH mats. 512 thr / 8 waves: wave w -> mat w>>2,
// 128-col strip (w&3)*128; acc[2 mt][8 nt] = 64 VGPR. K-loop = R19's verified
// skeleton (Bs 64KB gload_lds + As reg-staged dbuf, same swizzles, same
// B-row permutation row = strip + lc*8 + nt).
// LDS pool 80 KB (2 WG/CU): Bs [0,64K); As [64K,80K) = [mat][buf][32x64].
// Epilogue (every region reuse barrier-separated — the R6/R16 failure mode):
//   [bar] G+b1 (bf16) -> Bs region as [mat][32][512], chunk^(row&7)
//   [bar] coeff2's code VERBATIM (8 waves x 4 rows; bit-identical inputs/ops)
//         cshr -> dead As region
//   [bar] u build -> global (bit-identical to coeff2's u)
__global__ __launch_bounds__(512, 2) void mlpc2_kernel(
    const float* __restrict__ xs, const float* __restrict__ xe,
    const __bf16* __restrict__ W1b, const float* __restrict__ b1,
    const __bf16* __restrict__ w2p, const float* __restrict__ b2,
    const float* __restrict__ scale_p, __bf16* __restrict__ u) {
  __shared__ __align__(16) char pool[81920];

  const int tid = threadIdx.x;
  const int l = tid & 63, w = tid >> 6;      // 8 waves
  const int lc = l & 15, lg = l >> 4;
  const int m0 = blockIdx.x * 32;
  const int mat = w >> 2;
  const int strip = (w & 3) * 128;

  // ---- A staging: thread -> (amat = tid>>8, row = (tid>>3)&31, chunk aq = tid&7)
  const int amat = tid >> 8;
  const int arow = (tid >> 3) & 31;
  const int aq   = tid & 7;
  const float* asrc = (amat ? xe : xs) + (size_t)(m0 + arow)*DM + aq*8;

  auto stageB = [&](int k0) {
    #pragma unroll
    for (int c = 0; c < 8; ++c) {
      const int row = c*64 + (tid >> 3);
      const int sp = (tid & 7) ^ ((row >> 3) & 7);
      gload_lds16(W1b + (size_t)row*DM + k0 + sp*8, pool + c*8192 + tid*16);
    }
  };

  f32x4 ar0, ar1;
  auto loadA = [&](int k0) {
    const float* p = asrc + k0;
    ar0 = *(const f32x4*)(p);
    ar1 = *(const f32x4*)(p + 4);
  };
  auto writeA = [&](int buf) {
    const int e = arow & 7;
    *(bf16x8*)(pool + 65536 + amat*8192 + buf*4096 + arow*128 + ((aq ^ e)*16)) =
        cvt8(ar0, ar1);
  };

  f32x4 acc[2][8];
  #pragma unroll
  for (int a = 0; a < 2; ++a)
    #pragma unroll
    for (int b = 0; b < 8; ++b) acc[a][b] = (f32x4)0.f;

  loadA(0);
  stageB(0);
  writeA(0);

  for (int ks = 0; ks < 8; ++ks) {
    const int cb = ks & 1, nb = cb ^ 1;
    __syncthreads();                 // staging(ks) visible (vmcnt+lgkm)
    if (ks < 7) loadA((ks+1)*64);    // HBM loads issue early
    #pragma unroll
    for (int kk = 0; kk < 2; ++kk) {
      bf16x8 aF[2], bF[8];
      #pragma unroll
      for (int mt = 0; mt < 2; ++mt) {
        const int row = mt*16 + lc;
        const int sp = (kk*4 + lg) ^ (row & 7);
        aF[mt] = *(const bf16x8*)(pool + 65536 + mat*8192 + cb*4096 + row*128 + sp*16);
      }
      #pragma unroll
      for (int nt = 0; nt < 8; ++nt) {
        const int row = strip + lc*8 + nt;
        const int sp = (kk*4 + lg) ^ ((row >> 3) & 7);
        bF[nt] = *(const bf16x8*)(pool + row*128 + sp*16);
      }
      #pragma unroll
      for (int mt = 0; mt < 2; ++mt)
        #pragma unroll
        for (int nt = 0; nt < 8; ++nt)
          acc[mt][nt] = MFMA16(aF[mt], bF[nt], acc[mt][nt]);
    }
    if (ks < 7) {
      __syncthreads();               // all Bs/As reads for ks done
      stageB((ks+1)*64);
      writeA(nb);
    }
  }

  // ---- epilogue phase 1: G+b1 -> LDS (Bs region), [mat][row][512] bf16
  f32x4 b1lo = *(const f32x4*)(b1 + strip + lc*8);
  f32x4 b1hi = *(const f32x4*)(b1 + strip + lc*8 + 4);
  const float sclv = *scale_p;
  __syncthreads();                   // BARRIER: all Bs/As K-loop reads done
  #pragma unroll
  for (int mt = 0; mt < 2; ++mt) {
    #pragma unroll
    for (int rg = 0; rg < 4; ++rg) {
      const int row = mt*16 + lg*4 + rg;
      bf16x8 o;
      #pragma unroll
      for (int nt = 0; nt < 8; ++nt) {
        const float bb = (nt < 4) ? b1lo[nt] : b1hi[nt-4];
        o[nt] = (__bf16)(acc[mt][nt][rg] + bb);
      }
      const int chunk = ((w & 3)*16 + lc) ^ (row & 7);
      *(bf16x8*)(pool + mat*32768 + row*1024 + chunk*16) = o;
    }
  }
  __syncthreads();                   // BARRIER: G fully written

  // ---- epilogue phase 2: coeff2 VERBATIM (8 waves x 4 rows)
  float* cshr = (float*)(pool + 65536);   // alias dead As region: [32][8]
  {
    const int rib = w*4 + (l >> 4);       // row in block, 0..31
    const int ls = l & 15;

    float pz[4][8];
    #pragma unroll
    for (int st = 0; st < 4; ++st)
      #pragma unroll
      for (int r = 0; r < 8; ++r) pz[st][r] = 0.f;

    #pragma unroll
    for (int c = 0; c < 4; ++c) {
      const int nb = c*128 + ls*8;
      const int chunk = ((c*16 + ls) ^ (rib & 7));
      bf16x8 s8 = *(const bf16x8*)(pool +         rib*1024 + chunk*16);
      bf16x8 e8 = *(const bf16x8*)(pool + 32768 + rib*1024 + chunk*16);
      #pragma unroll
      for (int i = 0; i < 8; ++i) {
        const float sv = (float)s8[i];
        const float dv = (float)e8[i] - sv;
        bf16x8 wv8 = *(const bf16x8*)(w2p + (size_t)(nb + i)*8);
        float w2f[8];
        #pragma unroll
        for (int r = 0; r < 8; ++r) w2f[r] = (float)wv8[r];
        #pragma unroll
        for (int st = 0; st < 4; ++st) {
          const float t = 0.125f + 0.25f*(float)st;
          const float mid = fmaf(t, dv, sv);
          const float g = mid * fast_rcp(1.f + fast_exp2(-2.4554669f * mid));
          #pragma unroll
          for (int r = 0; r < 8; ++r) pz[st][r] = fmaf(g, w2f[r], pz[st][r]);
        }
      }
    }

    #pragma unroll
    for (int st = 0; st < 4; ++st)
      #pragma unroll
      for (int r = 0; r < 8; ++r) {
        float v = pz[st][r];
        v += __shfl_xor(v, 1); v += __shfl_xor(v, 2);
        v += __shfl_xor(v, 4); v += __shfl_xor(v, 8);
        pz[st][r] = v;
      }

    const int rown = ls & 7;
    const float b2r = b2[rown];
    float sum = 0.f;
    #pragma unroll
    for (int st = 0; st < 4; ++st) {
      const float z = pz[st][rown] + b2r;
      const float te = fast_exp2(2.8853901f * z);   // e^(2z); inf-safe
      sum += 1.f - 2.f * fast_rcp(te + 1.f);
    }
    const float cs_own = sum * 0.25f * sclv;        // * dt * scale
    if (ls < 8) cshr[rib*8 + ls] = cs_own;
  }
  __syncthreads();                   // BARRIER: cshr complete

  // ---- epilogue phase 3: u build -> global (thread -> row tid>>4, ls tid&15)
  {
    const int row = tid >> 4;
    const int ls = tid & 15;
    const float* csr = cshr + row*8;
    bf16x4 o;
    #pragma unroll
    for (int j = 0; j < 4; ++j) {
      const int k = ls*4 + j;
      float val;
      if (k < 8) {
        val = csr[k];
      } else if (k < 44) {
        const int p = k - 8;
        int r = (p>=8)+(p>=15)+(p>=21)+(p>=26)+(p>=30)+(p>=33)+(p>=35);
        const int baser = r*8 - ((r*(r-1))>>1);
        const int s2 = r + p - baser;
        val = 0.5f * csr[r] * csr[s2];
      } else if (k == 44) {
        val = 1.f;
      } else {
        val = 0.f;
      }
      o[j] = (__bf16)val;
    }
    *(bf16x4*)(u + (size_t)(m0 + row)*KU + ls*4) = o;
  }
}

// ---------------- K3: out[b][ij] = sum_k u[b][k] * Vt[ij][k]  (K=64) ----------------
// (R17 verified: LDS store-coalescing + NONTEMPORAL stores; ~6.4 TB/s write)
__global__ __launch_bounds__(256) void out_gemm_kernel(
    const __bf16* __restrict__ u, const __bf16* __restrict__ Vt,
    float* __restrict__ out) {
  __shared__ float Ls[16*256];   // 16 KB store-coalescing buffer
  const int bid = blockIdx.x;
  const int mb = bid >> 4, nbq = bid & 15;
  const int tid = threadIdx.x;
  const int l = tid & 63, wv = tid >> 6;
  const int lc = l & 15, lg = l >> 4;
  const int m0 = mb*64;
  const int n0 = nbq*256 + wv*64;

  f32x4 acc[4][4];
  #pragma unroll
  for (int a = 0; a < 4; ++a)
    #pragma unroll
    for (int b = 0; b < 4; ++b) acc[a][b] = (f32x4)0.f;

  #pragma unroll
  for (int ks = 0; ks < 2; ++ks) {
    const int k0 = ks*32 + lg*8;
    bf16x8 aF[4], bF[4];
    #pragma unroll
    for (int a = 0; a < 4; ++a)
      aF[a] = *(const bf16x8*)(u + (size_t)(m0 + a*16 + lc)*KU + k0);
    #pragma unroll
    for (int b = 0; b < 4; ++b)
      bF[b] = *(const bf16x8*)(Vt + (size_t)(n0 + lc*4 + b)*KU + k0);
    #pragma unroll
    for (int a = 0; a < 4; ++a)
      #pragma unroll
      for (int b = 0; b < 4; ++b)
        acc[a][b] = MFMA16(aF[a], bF[b], acc[a][b]);
  }

  #pragma unroll
  for (int a = 0; a < 4; ++a) {
    #pragma unroll
    for (int rg = 0; rg < 4; ++rg) {
      f32x4 o; o[0] = acc[a][0][rg]; o[1] = acc[a][1][rg];
      o[2] = acc[a][2][rg]; o[3] = acc[a][3][rg];
      *(f32x4*)(Ls + (lg*4 + rg)*256 + wv*64 + lc*4) = o;
    }
    __syncthreads();
    #pragma unroll
    for (int rr = 0; rr < 4; ++rr) {
      const int row = rr*4 + wv;
      f32x4 o = *(const f32x4*)(Ls + row*256 + l*4);
      __builtin_nontemporal_store(
          o, (f32x4*)(out + (size_t)(m0 + a*16 + row)*4096 + nbq*256 + l*4));
    }
    if (a < 3) __syncthreads();
  }
}

extern "C" void kernel_launch(void* const* d_in, const int* in_sizes, int n_in,
                              void* d_out, int out_size, void* d_ws, size_t ws_size,
                              hipStream_t stream) {
  const float* xs    = (const float*)d_in[0];
  const float* xe    = (const float*)d_in[1];
  const float* W1    = (const float*)d_in[2];
  const float* b1    = (const float*)d_in[3];
  const float* W2    = (const float*)d_in[4];
  const float* b2    = (const float*)d_in[5];
  const float* gen   = (const float*)d_in[6];
  const float* scale = (const float*)d_in[7];

  char* ws = (char*)d_ws;
  __bf16* W1b = (__bf16*)ws;                                    // 512 KB
  __bf16* u   = (__bf16*)(ws + 512*1024);                       // 2 MB
  __bf16* Vt  = (__bf16*)(ws + 512*1024 + 2*1024*1024);         // 512 KB
  __bf16* w2p = (__bf16*)(ws + 512*1024 + 2*1024*1024 + 512*1024); // 8 KB

  prep_kernel<<<298, 256, 0, stream>>>(W1, W2, gen, W1b, w2p, Vt);
  mlpc2_kernel<<<B_TOT/32, 512, 0, stream>>>(xs, xe, W1b, b1, w2p, b2, scale, u);
  out_gemm_kernel<<<256*16, 256, 0, stream>>>(u, Vt, (float*)d_out);
}